// Round 13
// baseline (3022.787 us; speedup 1.0000x reference)
//
#include <hip/hip_runtime.h>
#include <stdint.h>

// ModeloNeuralVasicek — FUSED producer-consumer kernel.
// Round 29: R28 post-mortem closed the books: S~29us fixed overhead,
// phase1 ~121us, phase2 ~120us, run SERIALLY. Phase2 block b consumes
// ws[b][64k..64k+63] at body k — fuse and overlap:
//  - one kernel, grid 64+40320: blocks 0..63 = consumers (dispatched FIRST
//    so they cannot be starved behind producers), rest = producers.
//  - producers chunk-major (gamma -> c,b,i): chunk c of EVERY b done at
//    ~(c/39.4)*T1. Each wave stores ws, __threadfence(); block does one
//    release atomicAdd(cnt[b*40+c]).
//  - consumers: R26 phase2 body VERBATIM except meanw LDS preload replaced
//    by per-body acquire-spin on cnt[b*40+k+1] (tgt 16; last chunk 6) +
//    direct ws load, placed between scan and EPI (latency overlapped).
//  - flags in d_ws tail (offset 645120, 10240B), hipMemsetAsync-zeroed.
// Deadlock-free: spinners hold <=64 CUs; producers always progress on the
// rest (7KB LDS, ILP-4 threefry tolerates 3 waves/SIMD).

#define NSTEPS 2520
#define NB 64
#define NT 256
#define NQ 256
#define NMAT 7
#define NBODY 40
#define P2BLK 64
#define NCHUNK 40

typedef uint32_t u32x4 __attribute__((ext_vector_type(4)));
typedef float f32x4 __attribute__((ext_vector_type(4)));

// 1-op rotate: alignbit(v,v,32-n) = (v<<n)|(v>>(32-n))
__device__ __forceinline__ uint32_t rotl32(uint32_t v, int n) {
  return __builtin_amdgcn_alignbit(v, v, (uint32_t)(32 - n));
}

// Threefry-2x32, 20 rounds — matches jax._src.prng.threefry2x32 exactly.
__device__ __forceinline__ void tf2x32(uint32_t k0, uint32_t k1,
                                       uint32_t x0, uint32_t x1,
                                       uint32_t& o0, uint32_t& o1) {
  const uint32_t k2 = k0 ^ k1 ^ 0x1BD11BDAu;
  x0 += k0; x1 += k1;
#define R4(a,b,c,d) \
  x0 += x1; x1 = rotl32(x1,(a)); x1 ^= x0; \
  x0 += x1; x1 = rotl32(x1,(b)); x1 ^= x0; \
  x0 += x1; x1 = rotl32(x1,(c)); x1 ^= x0; \
  x0 += x1; x1 = rotl32(x1,(d)); x1 ^= x0;
  R4(13,15,26,6)  x0 += k1; x1 += k2 + 1u;
  R4(17,29,16,24) x0 += k2; x1 += k0 + 2u;
  R4(13,15,26,6)  x0 += k0; x1 += k1 + 3u;
  R4(17,29,16,24) x0 += k1; x1 += k2 + 4u;
  R4(13,15,26,6)  x0 += k2; x1 += k0 + 5u;
  o0 = x0; o1 = x1;
}

// fast reciprocal: v_rcp + one Newton step (~1e-7 rel)
__device__ __forceinline__ float fast_rcp(float q) {
  float r = __builtin_amdgcn_rcpf(q);
  r = __builtin_fmaf(r, __builtin_fmaf(-q, r, 1.0f), r);
  return r;
}

// Eigen/XLA generic_fast_tanh_float (context aggregator only).
__device__ __forceinline__ float eigen_tanh(float a_x) {
  float x = fminf(fmaxf(a_x, -7.90531110763549805f), 7.90531110763549805f);
  float x2 = x * x;
  float p = __builtin_fmaf(x2, -2.76076847742355e-16f, 2.00018790482477e-13f);
  p = __builtin_fmaf(x2, p, -8.60467152213735e-11f);
  p = __builtin_fmaf(x2, p, 5.12229709037114e-08f);
  p = __builtin_fmaf(x2, p, 1.48572235717979e-05f);
  p = __builtin_fmaf(x2, p, 6.37261928875436e-04f);
  p = __builtin_fmaf(x2, p, 4.89352455891786e-03f);
  p = x * p;
  float q = __builtin_fmaf(x2, 1.19825839466702e-06f, 1.18534705686654e-04f);
  q = __builtin_fmaf(x2, q, 2.26843463243900e-03f);
  q = __builtin_fmaf(x2, q, 4.89352518554385e-03f);
  float rr = p / q;
  return (fabsf(a_x) < 0.0004f) ? a_x : rr;
}

// Eigen/XLA erf polynomial with rcp-division.
__device__ __forceinline__ float eigen_erf_fast(float a_x) {
  float x = fminf(fmaxf(a_x, -4.0f), 4.0f);
  float x2 = x * x;
  float p = __builtin_fmaf(x2, -2.72614225801306e-10f, 2.77068142495902e-08f);
  p = __builtin_fmaf(x2, p, -2.10102402082508e-06f);
  p = __builtin_fmaf(x2, p, -5.69250639462346e-05f);
  p = __builtin_fmaf(x2, p, -7.34990630326855e-04f);
  p = __builtin_fmaf(x2, p, -2.95459980854025e-03f);
  p = __builtin_fmaf(x2, p, -1.60960333262415e-02f);
  p = x * p;
  float q = __builtin_fmaf(x2, -1.45660718464996e-05f, -2.13374055278905e-04f);
  q = __builtin_fmaf(x2, q, -1.68282697438203e-03f);
  q = __builtin_fmaf(x2, q, -7.37332916720468e-03f);
  q = __builtin_fmaf(x2, q, -1.42647390514189e-02f);
  return p * fast_rcp(q);
}

__device__ __forceinline__ uint16_t f32_to_f16bits(float x) {
  _Float16 hv = (_Float16)x;  // RNE
  return __builtin_bit_cast(uint16_t, hv);
}

__device__ __forceinline__ uint32_t pack_f16x2(float lo, float hi) {
  return (uint32_t)f32_to_f16bits(lo) | ((uint32_t)f32_to_f16bits(hi) << 16);
}

// DPP add: v += dpp_move(v). 0x111..0x118 row_shr; 0x142/0x143 row_bcast.
template <int CTRL, int RMASK>
__device__ __forceinline__ float dpp_add(float v) {
  int x = __builtin_amdgcn_update_dpp(0, __float_as_int(v), CTRL, RMASK, 0xf, true);
  return v + __int_as_float(x);
}

// full-wave sum -> lane 63 (validated chain)
__device__ __forceinline__ float dpp_reduce63(float p) {
  p = dpp_add<0x111, 0xf>(p);
  p = dpp_add<0x112, 0xf>(p);
  p = dpp_add<0x114, 0xf>(p);
  p = dpp_add<0x118, 0xf>(p);
  p = dpp_add<0x142, 0xa>(p);
  p = dpp_add<0x143, 0xc>(p);
  return p;
}

// DPP move with explicit identity; RMASK gates receiving rows (others keep
// OLD); bound_ctrl=false keeps OLD for no-src lanes.
template <int CTRL, int RMASK>
__device__ __forceinline__ float dpp_mov(float v, float old) {
  int x = __builtin_amdgcn_update_dpp(__float_as_int(old), __float_as_int(v),
                                      CTRL, RMASK, 0xf, false);
  return __int_as_float(x);
}

__device__ __forceinline__ float readlane_f(float v, int l) {
  return __int_as_float(__builtin_amdgcn_readlane(__float_as_int(v), l));
}

// acquire-spin until cnt[idx] >= tgt (uniform across the block)
__device__ __forceinline__ void spin_chunk(const uint32_t* cnt, int idx,
                                           uint32_t tgt) {
  while (__hip_atomic_load(&cnt[idx], __ATOMIC_ACQUIRE,
                           __HIP_MEMORY_SCOPE_AGENT) < tgt) {
    __builtin_amdgcn_s_sleep(8);
  }
}

#define DTF  0.00396825396825396826f
#define SQDT 0.06299407883487120442f
#define TSTEP (1.0f / 2519.0f)
#define TSC      64.0f
#define TSC_INV  0.015625f
#define TSC_T    1024.0f
#define TSCT_INV 0.0009765625f
#define INV_SQRT2 0.7071067811865475f
#define PHI_C     0.3989422804014327f
#define NEG_LN2  -0.69314718055994530942f
#define LG2_W5   -7.2134752044448170368f
#define NRM_C    0.08908708063747479f

// ---- B-fragment machinery, k-PERMUTED (unchanged from R20/R23/R26) ----
#define BDECL(T, C) u32x4 b_##T##_##C;
#define BINIT(T, C) { \
  const int col_ = 16 * (4 * half + (C)) + n; \
  const int r0_ = 16 * (T) + 4 * q; \
  b_##T##_##C = (u32x4){ \
    pack_f16x2(W2src[(r0_ + 0) * 128 + col_], W2src[(r0_ + 64) * 128 + col_]), \
    pack_f16x2(W2src[(r0_ + 1) * 128 + col_], W2src[(r0_ + 65) * 128 + col_]), \
    pack_f16x2(W2src[(r0_ + 2) * 128 + col_], W2src[(r0_ + 66) * 128 + col_]), \
    pack_f16x2(W2src[(r0_ + 3) * 128 + col_], W2src[(r0_ + 67) * 128 + col_])}; \
  asm volatile("" : "+a"(b_##T##_##C)); /* pin in AGPR quad */ \
}
#define MFMA1(ACC, AF, BF) \
  asm("v_mfma_f32_16x16x32_f16 %0, %1, %2, %0" : "+v"(ACC) : "v"(AF), "a"(BF));

// one-eval layer-1 for a batch (R26): regions 0=val,1=dr*64,2=dt*1024.
#define STAGE3M(TV, SLOT, A_) { \
  float pre_ = __builtin_fmaf((TV), w11, __builtin_fmaf((A_), w10, c1)); \
  float e_ = eigen_erf_fast(pre_ * INV_SQRT2); \
  float cg_ = (e_ + 1.0f) * 0.5f; \
  float v_ = pre_ * cg_; \
  float ph_ = PHI_C * __expf(-0.5f * pre_ * pre_); \
  float gp_ = __builtin_fmaf(pre_, ph_, cg_); \
  ((uint16_t*)&h1x[SLOT][mlp][0][0])[2 * lane + half] = f32_to_f16bits(v_); \
  ((uint16_t*)&h1x[SLOT][mlp][1][0])[2 * lane + half] = f32_to_f16bits(gp_ * w10S); \
  ((uint16_t*)&h1x[SLOT][mlp][2][0])[2 * lane + half] = f32_to_f16bits(gp_ * w11T); \
}

// ---------------- FUSED kernel: 64 consumers + 40320 producers -------------
__global__
__attribute__((amdgpu_flat_work_group_size(256, 256)))
__attribute__((amdgpu_waves_per_eu(1, 8)))
void vasicek_fused(
    const float* __restrict__ X, const float* __restrict__ r_ult,
    const float* __restrict__ mats,
    const float* __restrict__ Wp, const float* __restrict__ bp,
    const float* __restrict__ ln_g, const float* __restrict__ ln_b,
    const float* __restrict__ muW1, const float* __restrict__ mub1,
    const float* __restrict__ muW2, const float* __restrict__ mub2,
    const float* __restrict__ muW3, const float* __restrict__ mub3,
    const float* __restrict__ siW1, const float* __restrict__ sib1,
    const float* __restrict__ siW2, const float* __restrict__ sib2,
    const float* __restrict__ siW3, const float* __restrict__ sib3,
    float* __restrict__ ws, uint32_t* __restrict__ cnt,
    float* __restrict__ out) {
  __shared__ __align__(16) uint32_t h1x[2][2][4][68];
  __shared__ float part[256];
  __shared__ float mbuf[64];
  __shared__ float ctx_lds[192];
  __shared__ __align__(16) float msum[2][4][4];   // [slot][wave][PV,PR,PT,pad]

  const int bid = blockIdx.x;
  const int t = threadIdx.x;
  const int lane = t & 63;
  const int wv = t >> 6;

  if (bid >= P2BLK) {
    // ================= producer (phase1), chunk-major =================
    const int gamma = bid - P2BLK;
    int pb, pc, pi;
    if (gamma < 39936) {            // full chunks: 39 x 64b x 16blk
      pc = gamma >> 10;
      const int rr = gamma & 1023;
      pb = rr >> 4;
      pi = rr & 15;
    } else {                        // partial chunk 39: 64b x 6blk
      const int d = gamma - 39936;
      pb = d / 6;
      pi = d - 6 * pb;
      pc = 39;
    }
    const int s = 64 * pc + 4 * pi + wv;

    uint32_t kA, kB;
    tf2x32(0u, 1u, 0u, (uint32_t)s, kA, kB);      // split(key(1))[s]
    const uint32_t k2 = kA ^ kB ^ 0x1BD11BDAu;
    const uint32_t x1base = (uint32_t)(pb * NQ + lane) + kB;

    const float MINVAL = -0.999999940395355224609375f;
    float sum = 0.f;
#pragma unroll
    for (int i = 0; i < 4; ++i) {
      uint32_t x0 = kA, x1 = x1base + (uint32_t)(i * 64);
      R4(13,15,26,6)  x0 += kB; x1 += k2 + 1u;
      R4(17,29,16,24) x0 += k2; x1 += kA + 2u;
      R4(13,15,26,6)  x0 += kA; x1 += kB + 3u;
      R4(17,29,16,24) x0 += kB; x1 += k2 + 4u;
      R4(13,15,26,6)  x0 += k2; x1 += kA + 5u;
      const uint32_t bits = x0 ^ x1;

      uint32_t fb = (bits >> 9) | 0x3F800000u;
      float u = __builtin_fmaf(__uint_as_float(fb) - 1.0f, 2.0f, MINVAL);
      u = fmaxf(u, MINVAL);
      float omsq = __builtin_fmaf(u, -u, 1.0f);
      float lg = __builtin_amdgcn_logf(omsq);
      float wc = __builtin_fmaf(lg, NEG_LN2, -2.5f);
      float p = 2.81022636e-08f;
      p = __builtin_fmaf(p, wc, 3.43273939e-07f);
      p = __builtin_fmaf(p, wc, -3.5233877e-06f);
      p = __builtin_fmaf(p, wc, -4.39150654e-06f);
      p = __builtin_fmaf(p, wc, 0.00021858087f);
      p = __builtin_fmaf(p, wc, -0.00125372503f);
      p = __builtin_fmaf(p, wc, -0.00417768164f);
      p = __builtin_fmaf(p, wc, 0.246640727f);
      p = __builtin_fmaf(p, wc, 1.50140941f);
      if (__ballot(lg <= LG2_W5)) {                // rare (~0.3% lanes)
        float w = lg * NEG_LN2;
        float wsr = sqrtf(w) - 3.0f;
        float pr = -0.000200214257f;
        pr = __builtin_fmaf(pr, wsr, 0.000100950558f);
        pr = __builtin_fmaf(pr, wsr, 0.00134934322f);
        pr = __builtin_fmaf(pr, wsr, -0.00367342844f);
        pr = __builtin_fmaf(pr, wsr, 0.00573950773f);
        pr = __builtin_fmaf(pr, wsr, -0.0076224613f);
        pr = __builtin_fmaf(pr, wsr, 0.00943887047f);
        pr = __builtin_fmaf(pr, wsr, 1.00167406f);
        pr = __builtin_fmaf(pr, wsr, 2.83297682f);
        p = (lg <= LG2_W5) ? pr : p;
      }
      sum = __builtin_fmaf(p * u, NRM_C, sum);
    }
    sum += __shfl_xor(sum, 32, 64); sum += __shfl_xor(sum, 16, 64);
    sum += __shfl_xor(sum, 8, 64);  sum += __shfl_xor(sum, 4, 64);
    sum += __shfl_xor(sum, 2, 64);  sum += __shfl_xor(sum, 1, 64);
    if (lane == 0) ws[pb * NSTEPS + s] = sum * (1.0f / 256.0f);
    __threadfence();                 // make stores device-visible
    __syncthreads();                 // all 4 waves stored+fenced
    if (t == 0)
      __hip_atomic_fetch_add(&cnt[pb * NCHUNK + pc], 1u,
                             __ATOMIC_RELEASE, __HIP_MEMORY_SCOPE_AGENT);
    return;
  }

  // ================= consumer (phase2, R26 structure) =================
  const int b = bid;

  // ---- context aggregator (all 256 threads, one T-row each) ----
  float h[64];
  {
    float x0 = X[(b * NT + t) * 2 + 0];
    float x1 = X[(b * NT + t) * 2 + 1];
    float s = 0.f;
#pragma unroll
    for (int c = 0; c < 64; ++c) {
      float pre = __builtin_fmaf(x1, Wp[64 + c], x0 * Wp[c]) + bp[c];
      h[c] = eigen_tanh(pre);
      s += h[c];
    }
    float m = s * 0.015625f;
    float vs = 0.f;
#pragma unroll
    for (int c = 0; c < 64; ++c) { float d = h[c] - m; vs = __builtin_fmaf(d, d, vs); }
    float den = sqrtf(vs * 0.015625f + 1e-5f);
#pragma unroll
    for (int c = 0; c < 64; ++c)
      h[c] = ((h[c] - m) / den) * ln_g[c] + ln_b[c];
  }
#pragma unroll
  for (int c = 0; c < 64; ++c) {
    float v = h[c];
    v += __shfl_xor(v, 32, 64); v += __shfl_xor(v, 16, 64);
    v += __shfl_xor(v, 8, 64);  v += __shfl_xor(v, 4, 64);
    v += __shfl_xor(v, 2, 64);  v += __shfl_xor(v, 1, 64);
    if (lane == 0) part[wv * 64 + c] = v;
  }
  __syncthreads();
  if (t < 64) {
    float m = ((part[t] + part[64 + t]) + (part[128 + t] + part[192 + t])) * (1.0f / 256.0f);
    mbuf[t] = m;
    ctx_lds[t] = m;
  }
  __syncthreads();
#pragma unroll
  for (int c = 0; c < 64; ++c) {
    float d = h[c] - mbuf[c];
    float v = d * d;
    v += __shfl_xor(v, 32, 64); v += __shfl_xor(v, 16, 64);
    v += __shfl_xor(v, 8, 64);  v += __shfl_xor(v, 4, 64);
    v += __shfl_xor(v, 2, 64);  v += __shfl_xor(v, 1, 64);
    if (lane == 0) part[wv * 64 + c] = v;
  }
  if (t == 255) {
#pragma unroll
    for (int c = 0; c < 64; ++c) ctx_lds[128 + c] = h[c];
  }
  __syncthreads();
  if (t < 64) {
    float vs = (part[t] + part[64 + t]) + (part[128 + t] + part[192 + t]);
    ctx_lds[64 + t] = sqrtf(vs / 255.0f);
  }
  __syncthreads();

  // ---- per-wave roles: mlp = wv>>1 (0=mu,1=si), half = wv&1 ----
  const int mlp = wv >> 1;
  const int half = wv & 1;
  const int jH = 64 * half + lane;
  const float* W1 = mlp == 0 ? muW1 : siW1;
  const float* W2src = mlp == 0 ? muW2 : siW2;
  float c1 = (mlp == 0 ? mub1 : sib1)[jH];
  for (int c = 0; c < 192; ++c) {
    const float cx = ctx_lds[c];
    c1 = __builtin_fmaf(cx, W1[(2 + c) * 128 + jH], c1);
  }
  const float w10 = W1[jH], w11 = W1[128 + jH];
  const float w10S = w10 * TSC;
  const float w11T = w11 * (TSTEP * TSC_T);
  const float b3mu = mub3[0], b3si = sib3[0];

  const int q = lane >> 4, n = lane & 15;
  const float* b2p = mlp == 0 ? mub2 : sib2;
  const float* w3p = mlp == 0 ? muW3 : siW3;
  const int colE = 64 * half + 16 * q + n;
  const float b2E = b2p[colE], w3E = w3p[colE];

  BDECL(0,0) BDECL(0,1) BDECL(0,2) BDECL(0,3)
  BDECL(1,0) BDECL(1,1) BDECL(1,2) BDECL(1,3)
  BDECL(2,0) BDECL(2,1) BDECL(2,2) BDECL(2,3)
  BDECL(3,0) BDECL(3,1) BDECL(3,2) BDECL(3,3)
  BINIT(0,0) BINIT(0,1) BINIT(0,2) BINIT(0,3)
  BINIT(1,0) BINIT(1,1) BINIT(1,2) BINIT(1,3)
  BINIT(2,0) BINIT(2,1) BINIT(2,2) BINIT(2,3)
  BINIT(3,0) BINIT(3,1) BINIT(3,2) BINIT(3,3)

  // zero region 3 (A-rows 3,7,11,15) for both slots of this wave's MLP
  h1x[0][mlp][3][lane] = 0u; h1x[1][mlp][3][lane] = 0u;
  if (lane < 4) { h1x[0][mlp][3][64 + lane] = 0u; h1x[1][mlp][3][64 + lane] = 0u; }

  const u32x4* hq0 = ((const u32x4*)&h1x[0][mlp][0][0]) + 17 * (n & 3) + q;
  const u32x4* hq1 = ((const u32x4*)&h1x[1][mlp][0][0]) + 17 * (n & 3) + q;

  const float r0 = r_ult[b];
  float r_s = r0;
  float aNow = r0, aUpd = r0, aMid = r0;
  float area_p = 0.f;
  const int sj = lane;
  const float jj = (float)sj - 31.5f;

  // ---- prologue: spin chunk 0, load its meanw; stage batch 0 ----
  spin_chunk(cnt, b * NCHUNK + 0, 16u);
  float mwj = ws[b * NSTEPS + sj];          // chunk 0 (also dummy for k=-1)
  STAGE3M(TSTEP * 31.5f, 0, r0)
  __syncthreads();

#pragma unroll 1
  for (int k = -1; k < NBODY; ++k) {
    const int sl = k & 1;
    const int so = sl ^ 1;

    f32x4 m0 = *(const f32x4*)&msum[sl][0][0];
    f32x4 m1 = *(const f32x4*)&msum[sl][1][0];
    f32x4 m2 = *(const f32x4*)&msum[sl][2][0];
    f32x4 m3 = *(const f32x4*)&msum[sl][3][0];
    const u32x4* hq = so ? hq1 : hq0;
    u32x4 af0 = hq[0], af1 = hq[4], af2 = hq[8], af3 = hq[12];

    // --- MFMA batch k+1 (matrix pipe) ---
    f32x4 ac0 = {0,0,0,0}, ac1 = {0,0,0,0}, ac2 = {0,0,0,0}, ac3 = {0,0,0,0};
    MFMA1(ac0, af0, b_0_0) MFMA1(ac1, af0, b_0_1) MFMA1(ac2, af0, b_0_2) MFMA1(ac3, af0, b_0_3)
    MFMA1(ac0, af1, b_1_0) MFMA1(ac1, af1, b_1_1) MFMA1(ac2, af1, b_1_2) MFMA1(ac3, af1, b_1_3)
    MFMA1(ac0, af2, b_2_0) MFMA1(ac1, af2, b_2_1) MFMA1(ac2, af2, b_2_2) MFMA1(ac3, af2, b_2_3)
    MFMA1(ac0, af3, b_3_0) MFMA1(ac1, af3, b_3_1) MFMA1(ac2, af3, b_3_2) MFMA1(ac3, af3, b_3_3)

    // --- STAGE3 batch k+2 (anchor aMid from previous rotation) ---
    STAGE3M(TSTEP * ((float)(64 * (k + 2)) + 31.5f), sl, aMid)

    // --- affine scan for batch k (lane sj = step 64k+sj) ---
    {
      float MV = (m0[0] + m1[0]) + b3mu;
      float MR = (m0[1] + m1[1]) * TSC_INV;
      float MT = (m0[2] + m1[2]) * TSCT_INV;
      float ZV = (m2[0] + m3[0]) + b3si;
      float ZR = (m2[1] + m3[1]) * TSC_INV;
      float ZT = (m2[2] + m3[2]) * TSCT_INV;
      float e_ = __expf(-fabsf(ZV));
      float sp = fmaxf(ZV, 0.f) + __logf(1.0f + e_) + 1e-5f;
      float inv = fast_rcp(1.0f + e_);
      float sgm = ZV > 0.f ? inv : 1.0f - inv;
      float hcv = 0.5f * sgm * (1.0f - sgm);
      float dzt = jj * ZT;
      float sigj = __builtin_fmaf(2.0f * hcv, dzt, sgm);
      float spj  = __builtin_fmaf(__builtin_fmaf(hcv, dzt, sgm), dzt, sp);
      float sZR = sigj * ZR;
      float beta = __builtin_fmaf(sZR, mwj, __builtin_fmaf(MR, DTF, 1.0f));
      float am_ = __builtin_fmaf(jj, MT, __builtin_fmaf(-aNow, MR, MV));
      float as_ = __builtin_fmaf(-aNow, sZR, spj);
      float alpha = __builtin_fmaf(am_, DTF, as_ * mwj);
      float B = beta, A = alpha;
      {
        float Bs = dpp_mov<0x111, 0xf>(B, 1.0f), As = dpp_mov<0x111, 0xf>(A, 0.0f);
        A = __builtin_fmaf(B, As, A); B = B * Bs;
        Bs = dpp_mov<0x112, 0xf>(B, 1.0f); As = dpp_mov<0x112, 0xf>(A, 0.0f);
        A = __builtin_fmaf(B, As, A); B = B * Bs;
        Bs = dpp_mov<0x114, 0xf>(B, 1.0f); As = dpp_mov<0x114, 0xf>(A, 0.0f);
        A = __builtin_fmaf(B, As, A); B = B * Bs;
        Bs = dpp_mov<0x118, 0xf>(B, 1.0f); As = dpp_mov<0x118, 0xf>(A, 0.0f);
        A = __builtin_fmaf(B, As, A); B = B * Bs;
        Bs = dpp_mov<0x142, 0xa>(B, 1.0f); As = dpp_mov<0x142, 0xa>(A, 0.0f);
        A = __builtin_fmaf(B, As, A); B = B * Bs;
        Bs = dpp_mov<0x143, 0xc>(B, 1.0f); As = dpp_mov<0x143, 0xc>(A, 0.0f);
        A = __builtin_fmaf(B, As, A); B = B * Bs;
      }
      float rho = __builtin_fmaf(B, r_s, A);
      if (k >= 0) {
        float contrib = (64 * k + sj) < NSTEPS ? rho * DTF : 0.f;
        area_p += contrib;
        float rn = readlane_f(rho, 63);
        float aNew = __builtin_fmaf(MV, 160.5f * DTF, rn);
        r_s = rn;
        aNow = aUpd; aUpd = aMid; aMid = aNew;
      }
    }

    // --- prefetch next chunk's meanw (spin overlaps EPI latency) ---
    float mw_next = 0.f;
    if (k < NBODY - 1) {
      const int nk = k + 1;
      spin_chunk(cnt, b * NCHUNK + nk, nk < 39 ? 16u : 6u);
      const int si = 64 * nk + sj;
      mw_next = si < NSTEPS ? ws[b * NSTEPS + si] : 0.f;
    }

    // --- MFMA dst -> VALU read hazard fence ---
    asm volatile("s_nop 7\n\ts_nop 7"
                 : "+v"(ac0), "+v"(ac1), "+v"(ac2), "+v"(ac3));

    // --- epilogue batch k+1: lane (q,n) handles its single column (C=q) ---
    {
      const f32x4 aq = q == 0 ? ac0 : q == 1 ? ac1 : q == 2 ? ac2 : ac3;
      float yv = aq[0] + b2E;
      float ytr = aq[1];
      float ytt = aq[2];
      float ev = eigen_erf_fast(yv * INV_SQRT2);
      float cv = (ev + 1.0f) * 0.5f;
      float pv = yv * cv * w3E;
      float phv = PHI_C * __expf(-0.5f * yv * yv);
      float g2p = __builtin_fmaf(yv, phv, cv) * w3E;
      float pr = g2p * ytr;
      float pt = g2p * ytt;
      pv = dpp_reduce63(pv);
      pr = dpp_reduce63(pr);
      pt = dpp_reduce63(pt);
      if (lane == 63) {
        *(f32x4*)&msum[so][wv][0] = (f32x4){pv, pr, pt, 0.f};
      }
    }
    mwj = mw_next;
    __syncthreads();  // publish msum[so] (batch k+1) + h1x[sl] (batch k+2)
  }

  // area: all 64 lanes hold distinct per-step partials
  float area = area_p;
  area += __shfl_xor(area, 1, 64);
  area += __shfl_xor(area, 2, 64);
  area += __shfl_xor(area, 4, 64);
  area += __shfl_xor(area, 8, 64);
  area += __shfl_xor(area, 16, 64);
  area += __shfl_xor(area, 32, 64);

  if (t < NMAT) {
    float mx = mats[0];
#pragma unroll
    for (int i = 1; i < NMAT; ++i) mx = fmaxf(mx, mats[i]);
    const float mm = mats[t];
    const float frac = mm / (mx + 1e-12f);
    out[b * NMAT + t] = (area * frac) / (mm + 1e-12f);
  }
}

extern "C" void kernel_launch(void* const* d_in, const int* in_sizes, int n_in,
                              void* d_out, int out_size, void* d_ws, size_t ws_size,
                              hipStream_t stream) {
  (void)in_sizes; (void)n_in; (void)ws_size; (void)out_size;
  const float* X      = (const float*)d_in[0];
  const float* r_ult  = (const float*)d_in[1];
  const float* mats   = (const float*)d_in[2];
  const float* Wp     = (const float*)d_in[3];
  const float* bp     = (const float*)d_in[4];
  const float* ln_g   = (const float*)d_in[5];
  const float* ln_b   = (const float*)d_in[6];
  const float* muW1   = (const float*)d_in[7];
  const float* mub1   = (const float*)d_in[8];
  const float* muW2   = (const float*)d_in[9];
  const float* mub2   = (const float*)d_in[10];
  const float* muW3   = (const float*)d_in[11];
  const float* mub3   = (const float*)d_in[12];
  const float* siW1   = (const float*)d_in[13];
  const float* sib1   = (const float*)d_in[14];
  const float* siW2   = (const float*)d_in[15];
  const float* sib2   = (const float*)d_in[16];
  const float* siW3   = (const float*)d_in[17];
  const float* sib3   = (const float*)d_in[18];
  float* ws = (float*)d_ws;                       // 645,120 B of meanw
  uint32_t* cnt = (uint32_t*)((char*)d_ws + NB * NSTEPS * 4);  // +10,240 B flags

  hipMemsetAsync(cnt, 0, NB * NCHUNK * sizeof(uint32_t), stream);
  hipLaunchKernelGGL(vasicek_fused,
                     dim3(P2BLK + 40320), dim3(256), 0, stream,
                     X, r_ult, mats, Wp, bp, ln_g, ln_b,
                     muW1, mub1, muW2, mub2, muW3, mub3,
                     siW1, sib1, siW2, sib2, siW3, sib3,
                     ws, cnt, (float*)d_out);
}

// Round 14
// 492.213 us; speedup vs baseline: 6.1412x; 6.1412x over previous
//
#include <hip/hip_runtime.h>
#include <stdint.h>

// ModeloNeuralVasicek — FUSED producer-consumer kernel, round 30.
// R29 (3023us) proved the fusion protocol CORRECT (absmax 0.0078125) but
// poisoned the memory system: 40320 per-block __threadfence (L2 flushes;
// WRITE_SIZE 1260->5600KB) + 16384-thread atomic spin. Fixes:
//  (1) no threadfence: waves' ws stores -> __syncthreads -> t0 RELEASE
//      atomicAdd is a valid happens-before chain.
//  (2) only t0 spins (ACQUIRE + s_sleep), placed just BEFORE the existing
//      end-of-body barrier; the barrier propagates the acquire block-wide.
//      ws loads move to next body top (latency hidden under MFMA/STAGE3).
//  (3) consumer CUs co-host producer blocks (17KB+6.6KB LDS fit) -> chip
//      stays loaded, no DVFS sag during the consumer phase.
// Producers chunk-major: chunk k of every b ready at ~(k/40)*T1; consumer
// body pace >= producer chunk pace -> consumers trail and finish ~T1+1 body.

#define NSTEPS 2520
#define NB 64
#define NT 256
#define NQ 256
#define NMAT 7
#define NBODY 40
#define P2BLK 64
#define NCHUNK 40

typedef uint32_t u32x4 __attribute__((ext_vector_type(4)));
typedef float f32x4 __attribute__((ext_vector_type(4)));

// 1-op rotate: alignbit(v,v,32-n) = (v<<n)|(v>>(32-n))
__device__ __forceinline__ uint32_t rotl32(uint32_t v, int n) {
  return __builtin_amdgcn_alignbit(v, v, (uint32_t)(32 - n));
}

// Threefry-2x32, 20 rounds — matches jax._src.prng.threefry2x32 exactly.
__device__ __forceinline__ void tf2x32(uint32_t k0, uint32_t k1,
                                       uint32_t x0, uint32_t x1,
                                       uint32_t& o0, uint32_t& o1) {
  const uint32_t k2 = k0 ^ k1 ^ 0x1BD11BDAu;
  x0 += k0; x1 += k1;
#define R4(a,b,c,d) \
  x0 += x1; x1 = rotl32(x1,(a)); x1 ^= x0; \
  x0 += x1; x1 = rotl32(x1,(b)); x1 ^= x0; \
  x0 += x1; x1 = rotl32(x1,(c)); x1 ^= x0; \
  x0 += x1; x1 = rotl32(x1,(d)); x1 ^= x0;
  R4(13,15,26,6)  x0 += k1; x1 += k2 + 1u;
  R4(17,29,16,24) x0 += k2; x1 += k0 + 2u;
  R4(13,15,26,6)  x0 += k0; x1 += k1 + 3u;
  R4(17,29,16,24) x0 += k1; x1 += k2 + 4u;
  R4(13,15,26,6)  x0 += k2; x1 += k0 + 5u;
  o0 = x0; o1 = x1;
}

// fast reciprocal: v_rcp + one Newton step (~1e-7 rel)
__device__ __forceinline__ float fast_rcp(float q) {
  float r = __builtin_amdgcn_rcpf(q);
  r = __builtin_fmaf(r, __builtin_fmaf(-q, r, 1.0f), r);
  return r;
}

// Eigen/XLA generic_fast_tanh_float (context aggregator only).
__device__ __forceinline__ float eigen_tanh(float a_x) {
  float x = fminf(fmaxf(a_x, -7.90531110763549805f), 7.90531110763549805f);
  float x2 = x * x;
  float p = __builtin_fmaf(x2, -2.76076847742355e-16f, 2.00018790482477e-13f);
  p = __builtin_fmaf(x2, p, -8.60467152213735e-11f);
  p = __builtin_fmaf(x2, p, 5.12229709037114e-08f);
  p = __builtin_fmaf(x2, p, 1.48572235717979e-05f);
  p = __builtin_fmaf(x2, p, 6.37261928875436e-04f);
  p = __builtin_fmaf(x2, p, 4.89352455891786e-03f);
  p = x * p;
  float q = __builtin_fmaf(x2, 1.19825839466702e-06f, 1.18534705686654e-04f);
  q = __builtin_fmaf(x2, q, 2.26843463243900e-03f);
  q = __builtin_fmaf(x2, q, 4.89352518554385e-03f);
  float rr = p / q;
  return (fabsf(a_x) < 0.0004f) ? a_x : rr;
}

// Eigen/XLA erf polynomial with rcp-division.
__device__ __forceinline__ float eigen_erf_fast(float a_x) {
  float x = fminf(fmaxf(a_x, -4.0f), 4.0f);
  float x2 = x * x;
  float p = __builtin_fmaf(x2, -2.72614225801306e-10f, 2.77068142495902e-08f);
  p = __builtin_fmaf(x2, p, -2.10102402082508e-06f);
  p = __builtin_fmaf(x2, p, -5.69250639462346e-05f);
  p = __builtin_fmaf(x2, p, -7.34990630326855e-04f);
  p = __builtin_fmaf(x2, p, -2.95459980854025e-03f);
  p = __builtin_fmaf(x2, p, -1.60960333262415e-02f);
  p = x * p;
  float q = __builtin_fmaf(x2, -1.45660718464996e-05f, -2.13374055278905e-04f);
  q = __builtin_fmaf(x2, q, -1.68282697438203e-03f);
  q = __builtin_fmaf(x2, q, -7.37332916720468e-03f);
  q = __builtin_fmaf(x2, q, -1.42647390514189e-02f);
  return p * fast_rcp(q);
}

__device__ __forceinline__ uint16_t f32_to_f16bits(float x) {
  _Float16 hv = (_Float16)x;  // RNE
  return __builtin_bit_cast(uint16_t, hv);
}

__device__ __forceinline__ uint32_t pack_f16x2(float lo, float hi) {
  return (uint32_t)f32_to_f16bits(lo) | ((uint32_t)f32_to_f16bits(hi) << 16);
}

// DPP add: v += dpp_move(v). 0x111..0x118 row_shr; 0x142/0x143 row_bcast.
template <int CTRL, int RMASK>
__device__ __forceinline__ float dpp_add(float v) {
  int x = __builtin_amdgcn_update_dpp(0, __float_as_int(v), CTRL, RMASK, 0xf, true);
  return v + __int_as_float(x);
}

// full-wave sum -> lane 63 (validated chain)
__device__ __forceinline__ float dpp_reduce63(float p) {
  p = dpp_add<0x111, 0xf>(p);
  p = dpp_add<0x112, 0xf>(p);
  p = dpp_add<0x114, 0xf>(p);
  p = dpp_add<0x118, 0xf>(p);
  p = dpp_add<0x142, 0xa>(p);
  p = dpp_add<0x143, 0xc>(p);
  return p;
}

// DPP move with explicit identity; RMASK gates receiving rows (others keep
// OLD); bound_ctrl=false keeps OLD for no-src lanes.
template <int CTRL, int RMASK>
__device__ __forceinline__ float dpp_mov(float v, float old) {
  int x = __builtin_amdgcn_update_dpp(__float_as_int(old), __float_as_int(v),
                                      CTRL, RMASK, 0xf, false);
  return __int_as_float(x);
}

__device__ __forceinline__ float readlane_f(float v, int l) {
  return __int_as_float(__builtin_amdgcn_readlane(__float_as_int(v), l));
}

#define DTF  0.00396825396825396826f
#define SQDT 0.06299407883487120442f
#define TSTEP (1.0f / 2519.0f)
#define TSC      64.0f
#define TSC_INV  0.015625f
#define TSC_T    1024.0f
#define TSCT_INV 0.0009765625f
#define INV_SQRT2 0.7071067811865475f
#define PHI_C     0.3989422804014327f
#define NEG_LN2  -0.69314718055994530942f
#define LG2_W5   -7.2134752044448170368f
#define NRM_C    0.08908708063747479f

// ---- B-fragment machinery, k-PERMUTED (unchanged from R20/R23/R26) ----
#define BDECL(T, C) u32x4 b_##T##_##C;
#define BINIT(T, C) { \
  const int col_ = 16 * (4 * half + (C)) + n; \
  const int r0_ = 16 * (T) + 4 * q; \
  b_##T##_##C = (u32x4){ \
    pack_f16x2(W2src[(r0_ + 0) * 128 + col_], W2src[(r0_ + 64) * 128 + col_]), \
    pack_f16x2(W2src[(r0_ + 1) * 128 + col_], W2src[(r0_ + 65) * 128 + col_]), \
    pack_f16x2(W2src[(r0_ + 2) * 128 + col_], W2src[(r0_ + 66) * 128 + col_]), \
    pack_f16x2(W2src[(r0_ + 3) * 128 + col_], W2src[(r0_ + 67) * 128 + col_])}; \
  asm volatile("" : "+a"(b_##T##_##C)); /* pin in AGPR quad */ \
}
#define MFMA1(ACC, AF, BF) \
  asm("v_mfma_f32_16x16x32_f16 %0, %1, %2, %0" : "+v"(ACC) : "v"(AF), "a"(BF));

// one-eval layer-1 for a batch (R26): regions 0=val,1=dr*64,2=dt*1024.
#define STAGE3M(TV, SLOT, A_) { \
  float pre_ = __builtin_fmaf((TV), w11, __builtin_fmaf((A_), w10, c1)); \
  float e_ = eigen_erf_fast(pre_ * INV_SQRT2); \
  float cg_ = (e_ + 1.0f) * 0.5f; \
  float v_ = pre_ * cg_; \
  float ph_ = PHI_C * __expf(-0.5f * pre_ * pre_); \
  float gp_ = __builtin_fmaf(pre_, ph_, cg_); \
  ((uint16_t*)&h1x[SLOT][mlp][0][0])[2 * lane + half] = f32_to_f16bits(v_); \
  ((uint16_t*)&h1x[SLOT][mlp][1][0])[2 * lane + half] = f32_to_f16bits(gp_ * w10S); \
  ((uint16_t*)&h1x[SLOT][mlp][2][0])[2 * lane + half] = f32_to_f16bits(gp_ * w11T); \
}

// ---------------- FUSED kernel: 64 consumers + 40320 producers -------------
__global__
__attribute__((amdgpu_flat_work_group_size(256, 256)))
void vasicek_fused(
    const float* __restrict__ X, const float* __restrict__ r_ult,
    const float* __restrict__ mats,
    const float* __restrict__ Wp, const float* __restrict__ bp,
    const float* __restrict__ ln_g, const float* __restrict__ ln_b,
    const float* __restrict__ muW1, const float* __restrict__ mub1,
    const float* __restrict__ muW2, const float* __restrict__ mub2,
    const float* __restrict__ muW3, const float* __restrict__ mub3,
    const float* __restrict__ siW1, const float* __restrict__ sib1,
    const float* __restrict__ siW2, const float* __restrict__ sib2,
    const float* __restrict__ siW3, const float* __restrict__ sib3,
    float* __restrict__ ws, uint32_t* __restrict__ cnt,
    float* __restrict__ out) {
  __shared__ __align__(16) uint32_t h1x[2][2][4][68];
  __shared__ float part[256];
  __shared__ float mbuf[64];
  __shared__ float ctx_lds[192];
  __shared__ __align__(16) float msum[2][4][4];   // [slot][wave][PV,PR,PT,pad]

  const int bid = blockIdx.x;
  const int t = threadIdx.x;
  const int lane = t & 63;
  const int wv = t >> 6;

  if (bid >= P2BLK) {
    // ================= producer (phase1), chunk-major =================
    const int gamma = bid - P2BLK;
    int pb, pc, pi;
    if (gamma < 39936) {            // full chunks: 39 x 64b x 16blk
      pc = gamma >> 10;
      const int rr = gamma & 1023;
      pb = rr >> 4;
      pi = rr & 15;
    } else {                        // partial chunk 39: 64b x 6blk
      const int d = gamma - 39936;
      pb = d / 6;
      pi = d - 6 * pb;
      pc = 39;
    }
    const int s = 64 * pc + 4 * pi + wv;

    uint32_t kA, kB;
    tf2x32(0u, 1u, 0u, (uint32_t)s, kA, kB);      // split(key(1))[s]
    const uint32_t k2 = kA ^ kB ^ 0x1BD11BDAu;
    const uint32_t x1base = (uint32_t)(pb * NQ + lane) + kB;

    const float MINVAL = -0.999999940395355224609375f;
    float sum = 0.f;
#pragma unroll
    for (int i = 0; i < 4; ++i) {
      uint32_t x0 = kA, x1 = x1base + (uint32_t)(i * 64);
      R4(13,15,26,6)  x0 += kB; x1 += k2 + 1u;
      R4(17,29,16,24) x0 += k2; x1 += kA + 2u;
      R4(13,15,26,6)  x0 += kA; x1 += kB + 3u;
      R4(17,29,16,24) x0 += kB; x1 += k2 + 4u;
      R4(13,15,26,6)  x0 += k2; x1 += kA + 5u;
      const uint32_t bits = x0 ^ x1;

      uint32_t fb = (bits >> 9) | 0x3F800000u;
      float u = __builtin_fmaf(__uint_as_float(fb) - 1.0f, 2.0f, MINVAL);
      u = fmaxf(u, MINVAL);
      float omsq = __builtin_fmaf(u, -u, 1.0f);
      float lg = __builtin_amdgcn_logf(omsq);
      float wc = __builtin_fmaf(lg, NEG_LN2, -2.5f);
      float p = 2.81022636e-08f;
      p = __builtin_fmaf(p, wc, 3.43273939e-07f);
      p = __builtin_fmaf(p, wc, -3.5233877e-06f);
      p = __builtin_fmaf(p, wc, -4.39150654e-06f);
      p = __builtin_fmaf(p, wc, 0.00021858087f);
      p = __builtin_fmaf(p, wc, -0.00125372503f);
      p = __builtin_fmaf(p, wc, -0.00417768164f);
      p = __builtin_fmaf(p, wc, 0.246640727f);
      p = __builtin_fmaf(p, wc, 1.50140941f);
      if (__ballot(lg <= LG2_W5)) {                // rare (~0.3% lanes)
        float w = lg * NEG_LN2;
        float wsr = sqrtf(w) - 3.0f;
        float pr = -0.000200214257f;
        pr = __builtin_fmaf(pr, wsr, 0.000100950558f);
        pr = __builtin_fmaf(pr, wsr, 0.00134934322f);
        pr = __builtin_fmaf(pr, wsr, -0.00367342844f);
        pr = __builtin_fmaf(pr, wsr, 0.00573950773f);
        pr = __builtin_fmaf(pr, wsr, -0.0076224613f);
        pr = __builtin_fmaf(pr, wsr, 0.00943887047f);
        pr = __builtin_fmaf(pr, wsr, 1.00167406f);
        pr = __builtin_fmaf(pr, wsr, 2.83297682f);
        p = (lg <= LG2_W5) ? pr : p;
      }
      sum = __builtin_fmaf(p * u, NRM_C, sum);
    }
    sum += __shfl_xor(sum, 32, 64); sum += __shfl_xor(sum, 16, 64);
    sum += __shfl_xor(sum, 8, 64);  sum += __shfl_xor(sum, 4, 64);
    sum += __shfl_xor(sum, 2, 64);  sum += __shfl_xor(sum, 1, 64);
    if (lane == 0) ws[pb * NSTEPS + s] = sum * (1.0f / 256.0f);
    __syncthreads();                 // all 4 waves' stores complete
    if (t == 0)                      // release makes them visible w/ cnt
      __hip_atomic_fetch_add(&cnt[pb * NCHUNK + pc], 1u,
                             __ATOMIC_RELEASE, __HIP_MEMORY_SCOPE_AGENT);
    return;
  }

  // ================= consumer (phase2, R26 structure) =================
  const int b = bid;

  // ---- context aggregator (all 256 threads, one T-row each) ----
  float h[64];
  {
    float x0 = X[(b * NT + t) * 2 + 0];
    float x1 = X[(b * NT + t) * 2 + 1];
    float s = 0.f;
#pragma unroll
    for (int c = 0; c < 64; ++c) {
      float pre = __builtin_fmaf(x1, Wp[64 + c], x0 * Wp[c]) + bp[c];
      h[c] = eigen_tanh(pre);
      s += h[c];
    }
    float m = s * 0.015625f;
    float vs = 0.f;
#pragma unroll
    for (int c = 0; c < 64; ++c) { float d = h[c] - m; vs = __builtin_fmaf(d, d, vs); }
    float den = sqrtf(vs * 0.015625f + 1e-5f);
#pragma unroll
    for (int c = 0; c < 64; ++c)
      h[c] = ((h[c] - m) / den) * ln_g[c] + ln_b[c];
  }
#pragma unroll
  for (int c = 0; c < 64; ++c) {
    float v = h[c];
    v += __shfl_xor(v, 32, 64); v += __shfl_xor(v, 16, 64);
    v += __shfl_xor(v, 8, 64);  v += __shfl_xor(v, 4, 64);
    v += __shfl_xor(v, 2, 64);  v += __shfl_xor(v, 1, 64);
    if (lane == 0) part[wv * 64 + c] = v;
  }
  __syncthreads();
  if (t < 64) {
    float m = ((part[t] + part[64 + t]) + (part[128 + t] + part[192 + t])) * (1.0f / 256.0f);
    mbuf[t] = m;
    ctx_lds[t] = m;
  }
  __syncthreads();
#pragma unroll
  for (int c = 0; c < 64; ++c) {
    float d = h[c] - mbuf[c];
    float v = d * d;
    v += __shfl_xor(v, 32, 64); v += __shfl_xor(v, 16, 64);
    v += __shfl_xor(v, 8, 64);  v += __shfl_xor(v, 4, 64);
    v += __shfl_xor(v, 2, 64);  v += __shfl_xor(v, 1, 64);
    if (lane == 0) part[wv * 64 + c] = v;
  }
  if (t == 255) {
#pragma unroll
    for (int c = 0; c < 64; ++c) ctx_lds[128 + c] = h[c];
  }
  __syncthreads();
  if (t < 64) {
    float vs = (part[t] + part[64 + t]) + (part[128 + t] + part[192 + t]);
    ctx_lds[64 + t] = sqrtf(vs / 255.0f);
  }
  __syncthreads();

  // ---- per-wave roles: mlp = wv>>1 (0=mu,1=si), half = wv&1 ----
  const int mlp = wv >> 1;
  const int half = wv & 1;
  const int jH = 64 * half + lane;
  const float* W1 = mlp == 0 ? muW1 : siW1;
  const float* W2src = mlp == 0 ? muW2 : siW2;
  float c1 = (mlp == 0 ? mub1 : sib1)[jH];
  for (int c = 0; c < 192; ++c) {
    const float cx = ctx_lds[c];
    c1 = __builtin_fmaf(cx, W1[(2 + c) * 128 + jH], c1);
  }
  const float w10 = W1[jH], w11 = W1[128 + jH];
  const float w10S = w10 * TSC;
  const float w11T = w11 * (TSTEP * TSC_T);
  const float b3mu = mub3[0], b3si = sib3[0];

  const int q = lane >> 4, n = lane & 15;
  const float* b2p = mlp == 0 ? mub2 : sib2;
  const float* w3p = mlp == 0 ? muW3 : siW3;
  const int colE = 64 * half + 16 * q + n;
  const float b2E = b2p[colE], w3E = w3p[colE];

  BDECL(0,0) BDECL(0,1) BDECL(0,2) BDECL(0,3)
  BDECL(1,0) BDECL(1,1) BDECL(1,2) BDECL(1,3)
  BDECL(2,0) BDECL(2,1) BDECL(2,2) BDECL(2,3)
  BDECL(3,0) BDECL(3,1) BDECL(3,2) BDECL(3,3)
  BINIT(0,0) BINIT(0,1) BINIT(0,2) BINIT(0,3)
  BINIT(1,0) BINIT(1,1) BINIT(1,2) BINIT(1,3)
  BINIT(2,0) BINIT(2,1) BINIT(2,2) BINIT(2,3)
  BINIT(3,0) BINIT(3,1) BINIT(3,2) BINIT(3,3)

  // zero region 3 (A-rows 3,7,11,15) for both slots of this wave's MLP
  h1x[0][mlp][3][lane] = 0u; h1x[1][mlp][3][lane] = 0u;
  if (lane < 4) { h1x[0][mlp][3][64 + lane] = 0u; h1x[1][mlp][3][64 + lane] = 0u; }

  const u32x4* hq0 = ((const u32x4*)&h1x[0][mlp][0][0]) + 17 * (n & 3) + q;
  const u32x4* hq1 = ((const u32x4*)&h1x[1][mlp][0][0]) + 17 * (n & 3) + q;

  const float r0 = r_ult[b];
  float r_s = r0;
  float aNow = r0, aUpd = r0, aMid = r0;
  float area_p = 0.f;
  const int sj = lane;
  const float jj = (float)sj - 31.5f;

  // ---- prologue: stage batch 0 (chunk 0 NOT yet needed) ----
  STAGE3M(TSTEP * 31.5f, 0, r0)
  // spin for chunk 0 (consumed by body k=0's load after this barrier)
  if (t == 0) {
    while (__hip_atomic_load(&cnt[b * NCHUNK + 0], __ATOMIC_ACQUIRE,
                             __HIP_MEMORY_SCOPE_AGENT) < 16u)
      __builtin_amdgcn_s_sleep(8);
  }
  __syncthreads();

#pragma unroll 1
  for (int k = -1; k < NBODY; ++k) {
    const int sl = k & 1;
    const int so = sl ^ 1;

    // --- meanw for batch k: direct global load (chunk k acquired at the
    //     end of body k-1; latency hidden under MFMA/STAGE3) ---
    float mwj = 0.f;
    if (k >= 0) {
      const int si = 64 * k + sj;
      mwj = si < NSTEPS ? ws[b * NSTEPS + si] : 0.f;
    }

    f32x4 m0 = *(const f32x4*)&msum[sl][0][0];
    f32x4 m1 = *(const f32x4*)&msum[sl][1][0];
    f32x4 m2 = *(const f32x4*)&msum[sl][2][0];
    f32x4 m3 = *(const f32x4*)&msum[sl][3][0];
    const u32x4* hq = so ? hq1 : hq0;
    u32x4 af0 = hq[0], af1 = hq[4], af2 = hq[8], af3 = hq[12];

    // --- MFMA batch k+1 (matrix pipe) ---
    f32x4 ac0 = {0,0,0,0}, ac1 = {0,0,0,0}, ac2 = {0,0,0,0}, ac3 = {0,0,0,0};
    MFMA1(ac0, af0, b_0_0) MFMA1(ac1, af0, b_0_1) MFMA1(ac2, af0, b_0_2) MFMA1(ac3, af0, b_0_3)
    MFMA1(ac0, af1, b_1_0) MFMA1(ac1, af1, b_1_1) MFMA1(ac2, af1, b_1_2) MFMA1(ac3, af1, b_1_3)
    MFMA1(ac0, af2, b_2_0) MFMA1(ac1, af2, b_2_1) MFMA1(ac2, af2, b_2_2) MFMA1(ac3, af2, b_2_3)
    MFMA1(ac0, af3, b_3_0) MFMA1(ac1, af3, b_3_1) MFMA1(ac2, af3, b_3_2) MFMA1(ac3, af3, b_3_3)

    // --- STAGE3 batch k+2 (anchor aMid from previous rotation) ---
    STAGE3M(TSTEP * ((float)(64 * (k + 2)) + 31.5f), sl, aMid)

    // --- affine scan for batch k (lane sj = step 64k+sj) ---
    {
      float MV = (m0[0] + m1[0]) + b3mu;
      float MR = (m0[1] + m1[1]) * TSC_INV;
      float MT = (m0[2] + m1[2]) * TSCT_INV;
      float ZV = (m2[0] + m3[0]) + b3si;
      float ZR = (m2[1] + m3[1]) * TSC_INV;
      float ZT = (m2[2] + m3[2]) * TSCT_INV;
      float e_ = __expf(-fabsf(ZV));
      float sp = fmaxf(ZV, 0.f) + __logf(1.0f + e_) + 1e-5f;
      float inv = fast_rcp(1.0f + e_);
      float sgm = ZV > 0.f ? inv : 1.0f - inv;
      float hcv = 0.5f * sgm * (1.0f - sgm);
      float dzt = jj * ZT;
      float sigj = __builtin_fmaf(2.0f * hcv, dzt, sgm);
      float spj  = __builtin_fmaf(__builtin_fmaf(hcv, dzt, sgm), dzt, sp);
      float sZR = sigj * ZR;
      float beta = __builtin_fmaf(sZR, mwj, __builtin_fmaf(MR, DTF, 1.0f));
      float am_ = __builtin_fmaf(jj, MT, __builtin_fmaf(-aNow, MR, MV));
      float as_ = __builtin_fmaf(-aNow, sZR, spj);
      float alpha = __builtin_fmaf(am_, DTF, as_ * mwj);
      float B = beta, A = alpha;
      {
        float Bs = dpp_mov<0x111, 0xf>(B, 1.0f), As = dpp_mov<0x111, 0xf>(A, 0.0f);
        A = __builtin_fmaf(B, As, A); B = B * Bs;
        Bs = dpp_mov<0x112, 0xf>(B, 1.0f); As = dpp_mov<0x112, 0xf>(A, 0.0f);
        A = __builtin_fmaf(B, As, A); B = B * Bs;
        Bs = dpp_mov<0x114, 0xf>(B, 1.0f); As = dpp_mov<0x114, 0xf>(A, 0.0f);
        A = __builtin_fmaf(B, As, A); B = B * Bs;
        Bs = dpp_mov<0x118, 0xf>(B, 1.0f); As = dpp_mov<0x118, 0xf>(A, 0.0f);
        A = __builtin_fmaf(B, As, A); B = B * Bs;
        Bs = dpp_mov<0x142, 0xa>(B, 1.0f); As = dpp_mov<0x142, 0xa>(A, 0.0f);
        A = __builtin_fmaf(B, As, A); B = B * Bs;
        Bs = dpp_mov<0x143, 0xc>(B, 1.0f); As = dpp_mov<0x143, 0xc>(A, 0.0f);
        A = __builtin_fmaf(B, As, A); B = B * Bs;
      }
      float rho = __builtin_fmaf(B, r_s, A);
      if (k >= 0) {
        float contrib = (64 * k + sj) < NSTEPS ? rho * DTF : 0.f;
        area_p += contrib;
        float rn = readlane_f(rho, 63);
        float aNew = __builtin_fmaf(MV, 160.5f * DTF, rn);
        r_s = rn;
        aNow = aUpd; aUpd = aMid; aMid = aNew;
      }
    }

    // --- MFMA dst -> VALU read hazard fence ---
    asm volatile("s_nop 7\n\ts_nop 7"
                 : "+v"(ac0), "+v"(ac1), "+v"(ac2), "+v"(ac3));

    // --- epilogue batch k+1: lane (q,n) handles its single column (C=q) ---
    {
      const f32x4 aq = q == 0 ? ac0 : q == 1 ? ac1 : q == 2 ? ac2 : ac3;
      float yv = aq[0] + b2E;
      float ytr = aq[1];
      float ytt = aq[2];
      float ev = eigen_erf_fast(yv * INV_SQRT2);
      float cv = (ev + 1.0f) * 0.5f;
      float pv = yv * cv * w3E;
      float phv = PHI_C * __expf(-0.5f * yv * yv);
      float g2p = __builtin_fmaf(yv, phv, cv) * w3E;
      float pr = g2p * ytr;
      float pt = g2p * ytt;
      pv = dpp_reduce63(pv);
      pr = dpp_reduce63(pr);
      pt = dpp_reduce63(pt);
      if (lane == 63) {
        *(f32x4*)&msum[so][wv][0] = (f32x4){pv, pr, pt, 0.f};
      }
    }

    // --- t0 acquires chunk k+1 before the barrier; barrier propagates ---
    if (t == 0 && k + 1 < NBODY) {
      const uint32_t tgt = (k + 1) < 39 ? 16u : 6u;
      while (__hip_atomic_load(&cnt[b * NCHUNK + k + 1], __ATOMIC_ACQUIRE,
                               __HIP_MEMORY_SCOPE_AGENT) < tgt)
        __builtin_amdgcn_s_sleep(8);
    }
    __syncthreads();  // publish msum[so] + h1x[sl]; propagate chunk k+1
  }

  // area: all 64 lanes hold distinct per-step partials
  float area = area_p;
  area += __shfl_xor(area, 1, 64);
  area += __shfl_xor(area, 2, 64);
  area += __shfl_xor(area, 4, 64);
  area += __shfl_xor(area, 8, 64);
  area += __shfl_xor(area, 16, 64);
  area += __shfl_xor(area, 32, 64);

  if (t < NMAT) {
    float mx = mats[0];
#pragma unroll
    for (int i = 1; i < NMAT; ++i) mx = fmaxf(mx, mats[i]);
    const float mm = mats[t];
    const float frac = mm / (mx + 1e-12f);
    out[b * NMAT + t] = (area * frac) / (mm + 1e-12f);
  }
}

extern "C" void kernel_launch(void* const* d_in, const int* in_sizes, int n_in,
                              void* d_out, int out_size, void* d_ws, size_t ws_size,
                              hipStream_t stream) {
  (void)in_sizes; (void)n_in; (void)ws_size; (void)out_size;
  const float* X      = (const float*)d_in[0];
  const float* r_ult  = (const float*)d_in[1];
  const float* mats   = (const float*)d_in[2];
  const float* Wp     = (const float*)d_in[3];
  const float* bp     = (const float*)d_in[4];
  const float* ln_g   = (const float*)d_in[5];
  const float* ln_b   = (const float*)d_in[6];
  const float* muW1   = (const float*)d_in[7];
  const float* mub1   = (const float*)d_in[8];
  const float* muW2   = (const float*)d_in[9];
  const float* mub2   = (const float*)d_in[10];
  const float* muW3   = (const float*)d_in[11];
  const float* mub3   = (const float*)d_in[12];
  const float* siW1   = (const float*)d_in[13];
  const float* sib1   = (const float*)d_in[14];
  const float* siW2   = (const float*)d_in[15];
  const float* sib2   = (const float*)d_in[16];
  const float* siW3   = (const float*)d_in[17];
  const float* sib3   = (const float*)d_in[18];
  float* ws = (float*)d_ws;                       // 645,120 B of meanw
  uint32_t* cnt = (uint32_t*)((char*)d_ws + NB * NSTEPS * 4);  // +10,240 B flags

  hipMemsetAsync(cnt, 0, NB * NCHUNK * sizeof(uint32_t), stream);
  hipLaunchKernelGGL(vasicek_fused,
                     dim3(P2BLK + 40320), dim3(256), 0, stream,
                     X, r_ult, mats, Wp, bp, ln_g, ln_b,
                     muW1, mub1, muW2, mub2, muW3, mub3,
                     siW1, sib1, siW2, sib2, siW3, sib3,
                     ws, cnt, (float*)d_out);
}

// Round 15
// 256.885 us; speedup vs baseline: 11.7671x; 1.9161x over previous
//
#include <hip/hip_runtime.h>
#include <stdint.h>

// ModeloNeuralVasicek — two-phase mean-recursion.
// Round 31: batch-128 pair-composed scan, unfused (R30 fusion post-mortem:
// shared regalloc throttles producers 80%->27.7% occupancy; abandoned).
// Base = R26 (270.3us total = S 28.9 + p1 121.5 + p2 ~120). Per-body cost
// is fixed-latency dominated (~7000cy @ batch64), and the one-eval body is
// batch-size independent except scan width. So: 128 steps/body, 20 bodies.
//  - lane sj composes steps {2sj,2sj+1} (beta/alpha pair-compose, ~25 ops),
//    validated 6-round 64-lane affine scan covers 128 steps.
//  - rho_even recovered via __shfl_up + fma; meanw read as float2.
//  - t-Taylor +-63.5 steps: 2nd-order h1 err ~1.7e-5 < f16 plateau.
//  - anchor drift distance 191.5 steps (160-step precedent held absmax).
// Phase1 byte-identical to R26 (121.5us, near VALU floor).

#define NSTEPS 2520
#define NB 64
#define NT 256
#define NQ 256
#define NMAT 7
#define NBODY 20
#define MWPAD 2560

typedef uint32_t u32x4 __attribute__((ext_vector_type(4)));
typedef float f32x4 __attribute__((ext_vector_type(4)));

// 1-op rotate: alignbit(v,v,32-n) = (v<<n)|(v>>(32-n))
__device__ __forceinline__ uint32_t rotl32(uint32_t v, int n) {
  return __builtin_amdgcn_alignbit(v, v, (uint32_t)(32 - n));
}

// Threefry-2x32, 20 rounds — matches jax._src.prng.threefry2x32 exactly.
__device__ __forceinline__ void tf2x32(uint32_t k0, uint32_t k1,
                                       uint32_t x0, uint32_t x1,
                                       uint32_t& o0, uint32_t& o1) {
  const uint32_t k2 = k0 ^ k1 ^ 0x1BD11BDAu;
  x0 += k0; x1 += k1;
#define R4(a,b,c,d) \
  x0 += x1; x1 = rotl32(x1,(a)); x1 ^= x0; \
  x0 += x1; x1 = rotl32(x1,(b)); x1 ^= x0; \
  x0 += x1; x1 = rotl32(x1,(c)); x1 ^= x0; \
  x0 += x1; x1 = rotl32(x1,(d)); x1 ^= x0;
  R4(13,15,26,6)  x0 += k1; x1 += k2 + 1u;
  R4(17,29,16,24) x0 += k2; x1 += k0 + 2u;
  R4(13,15,26,6)  x0 += k0; x1 += k1 + 3u;
  R4(17,29,16,24) x0 += k1; x1 += k2 + 4u;
  R4(13,15,26,6)  x0 += k2; x1 += k0 + 5u;
  o0 = x0; o1 = x1;
}

// fast reciprocal: v_rcp + one Newton step (~1e-7 rel)
__device__ __forceinline__ float fast_rcp(float q) {
  float r = __builtin_amdgcn_rcpf(q);
  r = __builtin_fmaf(r, __builtin_fmaf(-q, r, 1.0f), r);
  return r;
}

// Eigen/XLA generic_fast_tanh_float (context aggregator only).
__device__ __forceinline__ float eigen_tanh(float a_x) {
  float x = fminf(fmaxf(a_x, -7.90531110763549805f), 7.90531110763549805f);
  float x2 = x * x;
  float p = __builtin_fmaf(x2, -2.76076847742355e-16f, 2.00018790482477e-13f);
  p = __builtin_fmaf(x2, p, -8.60467152213735e-11f);
  p = __builtin_fmaf(x2, p, 5.12229709037114e-08f);
  p = __builtin_fmaf(x2, p, 1.48572235717979e-05f);
  p = __builtin_fmaf(x2, p, 6.37261928875436e-04f);
  p = __builtin_fmaf(x2, p, 4.89352455891786e-03f);
  p = x * p;
  float q = __builtin_fmaf(x2, 1.19825839466702e-06f, 1.18534705686654e-04f);
  q = __builtin_fmaf(x2, q, 2.26843463243900e-03f);
  q = __builtin_fmaf(x2, q, 4.89352518554385e-03f);
  float rr = p / q;
  return (fabsf(a_x) < 0.0004f) ? a_x : rr;
}

// Eigen/XLA erf polynomial with rcp-division.
__device__ __forceinline__ float eigen_erf_fast(float a_x) {
  float x = fminf(fmaxf(a_x, -4.0f), 4.0f);
  float x2 = x * x;
  float p = __builtin_fmaf(x2, -2.72614225801306e-10f, 2.77068142495902e-08f);
  p = __builtin_fmaf(x2, p, -2.10102402082508e-06f);
  p = __builtin_fmaf(x2, p, -5.69250639462346e-05f);
  p = __builtin_fmaf(x2, p, -7.34990630326855e-04f);
  p = __builtin_fmaf(x2, p, -2.95459980854025e-03f);
  p = __builtin_fmaf(x2, p, -1.60960333262415e-02f);
  p = x * p;
  float q = __builtin_fmaf(x2, -1.45660718464996e-05f, -2.13374055278905e-04f);
  q = __builtin_fmaf(x2, q, -1.68282697438203e-03f);
  q = __builtin_fmaf(x2, q, -7.37332916720468e-03f);
  q = __builtin_fmaf(x2, q, -1.42647390514189e-02f);
  return p * fast_rcp(q);
}

// XLA chlo.erf_inv f32 — phase 1 only. __logf ~1e-7 rel. Rare branch (w>=5,
// ~0.3% lanes) ballot-guarded: ~81% of waves skip it; bit-identical.
__device__ __forceinline__ float erfinv_xla(float x) {
  float w = -__logf((1.0f - x) * (1.0f + x));
  float wc = w - 2.5f;
  float p = 2.81022636e-08f;
  p = __builtin_fmaf(p, wc, 3.43273939e-07f);
  p = __builtin_fmaf(p, wc, -3.5233877e-06f);
  p = __builtin_fmaf(p, wc, -4.39150654e-06f);
  p = __builtin_fmaf(p, wc, 0.00021858087f);
  p = __builtin_fmaf(p, wc, -0.00125372503f);
  p = __builtin_fmaf(p, wc, -0.00417768164f);
  p = __builtin_fmaf(p, wc, 0.246640727f);
  p = __builtin_fmaf(p, wc, 1.50140941f);
  if (__ballot(w >= 5.0f)) {
    float ws = sqrtf(w) - 3.0f;
    float pr = -0.000200214257f;
    pr = __builtin_fmaf(pr, ws, 0.000100950558f);
    pr = __builtin_fmaf(pr, ws, 0.00134934322f);
    pr = __builtin_fmaf(pr, ws, -0.00367342844f);
    pr = __builtin_fmaf(pr, ws, 0.00573950773f);
    pr = __builtin_fmaf(pr, ws, -0.0076224613f);
    pr = __builtin_fmaf(pr, ws, 0.00943887047f);
    pr = __builtin_fmaf(pr, ws, 1.00167406f);
    pr = __builtin_fmaf(pr, ws, 2.83297682f);
    p = (w >= 5.0f) ? pr : p;
  }
  return p * x;
}

__device__ __forceinline__ uint16_t f32_to_f16bits(float x) {
  _Float16 hv = (_Float16)x;  // RNE
  return __builtin_bit_cast(uint16_t, hv);
}

__device__ __forceinline__ uint32_t pack_f16x2(float lo, float hi) {
  return (uint32_t)f32_to_f16bits(lo) | ((uint32_t)f32_to_f16bits(hi) << 16);
}

// DPP add: v += dpp_move(v). 0x111..0x118 row_shr; 0x142/0x143 row_bcast.
template <int CTRL, int RMASK>
__device__ __forceinline__ float dpp_add(float v) {
  int x = __builtin_amdgcn_update_dpp(0, __float_as_int(v), CTRL, RMASK, 0xf, true);
  return v + __int_as_float(x);
}

// full-wave sum -> lane 63 (validated chain)
__device__ __forceinline__ float dpp_reduce63(float p) {
  p = dpp_add<0x111, 0xf>(p);
  p = dpp_add<0x112, 0xf>(p);
  p = dpp_add<0x114, 0xf>(p);
  p = dpp_add<0x118, 0xf>(p);
  p = dpp_add<0x142, 0xa>(p);
  p = dpp_add<0x143, 0xc>(p);
  return p;
}

// DPP move with explicit identity; RMASK gates receiving rows (others keep
// OLD); bound_ctrl=false keeps OLD for no-src lanes.
template <int CTRL, int RMASK>
__device__ __forceinline__ float dpp_mov(float v, float old) {
  int x = __builtin_amdgcn_update_dpp(__float_as_int(old), __float_as_int(v),
                                      CTRL, RMASK, 0xf, false);
  return __int_as_float(x);
}

__device__ __forceinline__ float readlane_f(float v, int l) {
  return __int_as_float(__builtin_amdgcn_readlane(__float_as_int(v), l));
}

#define DTF  0.00396825396825396826f
#define SQDT 0.06299407883487120442f
#define TSTEP (1.0f / 2519.0f)
#define TSC      64.0f
#define TSC_INV  0.015625f
#define TSC_T    1024.0f
#define TSCT_INV 0.0009765625f
#define INV_SQRT2 0.7071067811865475f
#define PHI_C     0.3989422804014327f
#define NEG_LN2  -0.69314718055994530942f
#define LG2_W5   -7.2134752044448170368f
#define NRM_C    0.08908708063747479f

// ---------------- Phase 1: mean_dW[b][s] — fully parallel ----------------
__global__ __launch_bounds__(256)
void vasicek_phase1_meandw(float* __restrict__ ws) {
  const int tid = threadIdx.x;
  const int lane = tid & 63;
  const int wv = tid >> 6;
  const int wid = blockIdx.x * 4 + wv;          // 0 .. 64*2520-1
  const int b = wid / NSTEPS;
  const int s = wid - b * NSTEPS;

  uint32_t kA, kB;
  tf2x32(0u, 1u, 0u, (uint32_t)s, kA, kB);      // split(key(1))[s]
  const uint32_t k2 = kA ^ kB ^ 0x1BD11BDAu;
  const uint32_t x1base = (uint32_t)(b * NQ + lane) + kB;  // pre-keyed x1

  const float MINVAL = -0.999999940395355224609375f;
  float sum = 0.f;
#pragma unroll
  for (int i = 0; i < 4; ++i) {
    uint32_t x0 = kA, x1 = x1base + (uint32_t)(i * 64);
    R4(13,15,26,6)  x0 += kB; x1 += k2 + 1u;
    R4(17,29,16,24) x0 += k2; x1 += kA + 2u;
    R4(13,15,26,6)  x0 += kA; x1 += kB + 3u;
    R4(17,29,16,24) x0 += kB; x1 += k2 + 4u;
    R4(13,15,26,6)  x0 += k2; x1 += kA + 5u;
    const uint32_t bits = x0 ^ x1;

    uint32_t fb = (bits >> 9) | 0x3F800000u;
    float u = __builtin_fmaf(__uint_as_float(fb) - 1.0f, 2.0f, MINVAL);
    u = fmaxf(u, MINVAL);
    float omsq = __builtin_fmaf(u, -u, 1.0f);
    float lg = __builtin_amdgcn_logf(omsq);
    float wc = __builtin_fmaf(lg, NEG_LN2, -2.5f);
    float p = 2.81022636e-08f;
    p = __builtin_fmaf(p, wc, 3.43273939e-07f);
    p = __builtin_fmaf(p, wc, -3.5233877e-06f);
    p = __builtin_fmaf(p, wc, -4.39150654e-06f);
    p = __builtin_fmaf(p, wc, 0.00021858087f);
    p = __builtin_fmaf(p, wc, -0.00125372503f);
    p = __builtin_fmaf(p, wc, -0.00417768164f);
    p = __builtin_fmaf(p, wc, 0.246640727f);
    p = __builtin_fmaf(p, wc, 1.50140941f);
    if (__ballot(lg <= LG2_W5)) {                      // rare (~0.3% lanes)
      float w = lg * NEG_LN2;
      float wsr = sqrtf(w) - 3.0f;
      float pr = -0.000200214257f;
      pr = __builtin_fmaf(pr, wsr, 0.000100950558f);
      pr = __builtin_fmaf(pr, wsr, 0.00134934322f);
      pr = __builtin_fmaf(pr, wsr, -0.00367342844f);
      pr = __builtin_fmaf(pr, wsr, 0.00573950773f);
      pr = __builtin_fmaf(pr, wsr, -0.0076224613f);
      pr = __builtin_fmaf(pr, wsr, 0.00943887047f);
      pr = __builtin_fmaf(pr, wsr, 1.00167406f);
      pr = __builtin_fmaf(pr, wsr, 2.83297682f);
      p = (lg <= LG2_W5) ? pr : p;
    }
    sum = __builtin_fmaf(p * u, NRM_C, sum);
  }
  sum += __shfl_xor(sum, 32, 64); sum += __shfl_xor(sum, 16, 64);
  sum += __shfl_xor(sum, 8, 64);  sum += __shfl_xor(sum, 4, 64);
  sum += __shfl_xor(sum, 2, 64);  sum += __shfl_xor(sum, 1, 64);
  if (lane == 0) ws[b * NSTEPS + s] = sum * (1.0f / 256.0f);
}

// ---- B-fragment machinery, k-PERMUTED (unchanged from R20/R23/R26):
// B dword d of K-chunk T (lane q,n) holds W2 rows (16T+4q+d, 64+16T+4q+d)
// at column 16*(4*half+C) + n, f16x2 packed.
#define BDECL(T, C) u32x4 b_##T##_##C;
#define BINIT(T, C) { \
  const int col_ = 16 * (4 * half + (C)) + n; \
  const int r0_ = 16 * (T) + 4 * q; \
  b_##T##_##C = (u32x4){ \
    pack_f16x2(W2src[(r0_ + 0) * 128 + col_], W2src[(r0_ + 64) * 128 + col_]), \
    pack_f16x2(W2src[(r0_ + 1) * 128 + col_], W2src[(r0_ + 65) * 128 + col_]), \
    pack_f16x2(W2src[(r0_ + 2) * 128 + col_], W2src[(r0_ + 66) * 128 + col_]), \
    pack_f16x2(W2src[(r0_ + 3) * 128 + col_], W2src[(r0_ + 67) * 128 + col_])}; \
  asm volatile("" : "+a"(b_##T##_##C)); /* pin in AGPR quad */ \
}
#define MFMA1(ACC, AF, BF) \
  asm("v_mfma_f32_16x16x32_f16 %0, %1, %2, %0" : "+v"(ACC) : "v"(AF), "a"(BF));

// one-eval layer-1 for a batch: anchor A_, mid-time TV; writes regions
// 0=val, 1=d/dr*64, 2=d/dt_j*1024 (region 3 pre-zeroed).
#define STAGE3M(TV, SLOT, A_) { \
  float pre_ = __builtin_fmaf((TV), w11, __builtin_fmaf((A_), w10, c1)); \
  float e_ = eigen_erf_fast(pre_ * INV_SQRT2); \
  float cg_ = (e_ + 1.0f) * 0.5f; \
  float v_ = pre_ * cg_; \
  float ph_ = PHI_C * __expf(-0.5f * pre_ * pre_); \
  float gp_ = __builtin_fmaf(pre_, ph_, cg_); \
  ((uint16_t*)&h1x[SLOT][mlp][0][0])[2 * lane + half] = f32_to_f16bits(v_); \
  ((uint16_t*)&h1x[SLOT][mlp][1][0])[2 * lane + half] = f32_to_f16bits(gp_ * w10S); \
  ((uint16_t*)&h1x[SLOT][mlp][2][0])[2 * lane + half] = f32_to_f16bits(gp_ * w11T); \
}

// ---------------- Phase 2: scan, 64 blocks x 256 ---------------------------
__global__
__attribute__((amdgpu_flat_work_group_size(256, 256)))
__attribute__((amdgpu_waves_per_eu(1, 1)))
void vasicek_phase2_scan(
    const float* __restrict__ X, const float* __restrict__ r_ult,
    const float* __restrict__ mats,
    const float* __restrict__ Wp, const float* __restrict__ bp,
    const float* __restrict__ ln_g, const float* __restrict__ ln_b,
    const float* __restrict__ muW1, const float* __restrict__ mub1,
    const float* __restrict__ muW2, const float* __restrict__ mub2,
    const float* __restrict__ muW3, const float* __restrict__ mub3,
    const float* __restrict__ siW1, const float* __restrict__ sib1,
    const float* __restrict__ siW2, const float* __restrict__ sib2,
    const float* __restrict__ siW3, const float* __restrict__ sib3,
    const float* __restrict__ ws, float* __restrict__ out) {
  // [slot][mlp][region: 0=val,1=dr,2=dt,3=zero][68 dw] (stride 272B==16 mod 128)
  __shared__ __align__(16) uint32_t h1x[2][2][4][68];
  __shared__ __align__(16) float meanw[MWPAD];
  __shared__ float part[256];
  __shared__ float mbuf[64];
  __shared__ float ctx_lds[192];
  __shared__ __align__(16) float msum[2][4][4];   // [slot][wave][PV,PR,PT,pad]

  const int t = threadIdx.x;
  const int b = blockIdx.x;
  const int lane = t & 63;
  const int wv = t >> 6;

  for (int i = t; i < MWPAD; i += 256)
    meanw[i] = i < NSTEPS ? ws[b * NSTEPS + i] : 0.f;

  // ---- context aggregator (all 256 threads, one T-row each) ----
  float h[64];
  {
    float x0 = X[(b * NT + t) * 2 + 0];
    float x1 = X[(b * NT + t) * 2 + 1];
    float s = 0.f;
#pragma unroll
    for (int c = 0; c < 64; ++c) {
      float pre = __builtin_fmaf(x1, Wp[64 + c], x0 * Wp[c]) + bp[c];
      h[c] = eigen_tanh(pre);
      s += h[c];
    }
    float m = s * 0.015625f;
    float vs = 0.f;
#pragma unroll
    for (int c = 0; c < 64; ++c) { float d = h[c] - m; vs = __builtin_fmaf(d, d, vs); }
    float den = sqrtf(vs * 0.015625f + 1e-5f);
#pragma unroll
    for (int c = 0; c < 64; ++c)
      h[c] = ((h[c] - m) / den) * ln_g[c] + ln_b[c];
  }
#pragma unroll
  for (int c = 0; c < 64; ++c) {
    float v = h[c];
    v += __shfl_xor(v, 32, 64); v += __shfl_xor(v, 16, 64);
    v += __shfl_xor(v, 8, 64);  v += __shfl_xor(v, 4, 64);
    v += __shfl_xor(v, 2, 64);  v += __shfl_xor(v, 1, 64);
    if (lane == 0) part[wv * 64 + c] = v;
  }
  __syncthreads();
  if (t < 64) {
    float m = ((part[t] + part[64 + t]) + (part[128 + t] + part[192 + t])) * (1.0f / 256.0f);
    mbuf[t] = m;
    ctx_lds[t] = m;
  }
  __syncthreads();
#pragma unroll
  for (int c = 0; c < 64; ++c) {
    float d = h[c] - mbuf[c];
    float v = d * d;
    v += __shfl_xor(v, 32, 64); v += __shfl_xor(v, 16, 64);
    v += __shfl_xor(v, 8, 64);  v += __shfl_xor(v, 4, 64);
    v += __shfl_xor(v, 2, 64);  v += __shfl_xor(v, 1, 64);
    if (lane == 0) part[wv * 64 + c] = v;
  }
  if (t == 255) {
#pragma unroll
    for (int c = 0; c < 64; ++c) ctx_lds[128 + c] = h[c];
  }
  __syncthreads();
  if (t < 64) {
    float vs = (part[t] + part[64 + t]) + (part[128 + t] + part[192 + t]);
    ctx_lds[64 + t] = sqrtf(vs / 255.0f);
  }
  __syncthreads();

  // ---- per-wave roles: mlp = wv>>1 (0=mu,1=si), half = wv&1 ----
  const int mlp = wv >> 1;
  const int half = wv & 1;
  const int jH = 64 * half + lane;            // layer-1 element ownership
  const float* W1 = mlp == 0 ? muW1 : siW1;
  const float* W2src = mlp == 0 ? muW2 : siW2;
  float c1 = (mlp == 0 ? mub1 : sib1)[jH];
  for (int c = 0; c < 192; ++c) {
    const float cx = ctx_lds[c];
    c1 = __builtin_fmaf(cx, W1[(2 + c) * 128 + jH], c1);
  }
  const float w10 = W1[jH], w11 = W1[128 + jH];
  const float w10S = w10 * TSC;
  const float w11T = w11 * (TSTEP * TSC_T);
  const float b3mu = mub3[0], b3si = sib3[0];

  const int q = lane >> 4, n = lane & 15;

  // per-lane epilogue constants: this lane's single column (chunk C = q)
  const float* b2p = mlp == 0 ? mub2 : sib2;
  const float* w3p = mlp == 0 ? muW3 : siW3;
  const int colE = 64 * half + 16 * q + n;
  const float b2E = b2p[colE], w3E = w3p[colE];

  // this wave's 4 col-tiles of its W2 -> 16 AGPR quads (one-time; pinned)
  BDECL(0,0) BDECL(0,1) BDECL(0,2) BDECL(0,3)
  BDECL(1,0) BDECL(1,1) BDECL(1,2) BDECL(1,3)
  BDECL(2,0) BDECL(2,1) BDECL(2,2) BDECL(2,3)
  BDECL(3,0) BDECL(3,1) BDECL(3,2) BDECL(3,3)
  BINIT(0,0) BINIT(0,1) BINIT(0,2) BINIT(0,3)
  BINIT(1,0) BINIT(1,1) BINIT(1,2) BINIT(1,3)
  BINIT(2,0) BINIT(2,1) BINIT(2,2) BINIT(2,3)
  BINIT(3,0) BINIT(3,1) BINIT(3,2) BINIT(3,3)

  // zero region 3 (A-rows 3,7,11,15) for both slots of this wave's MLP
  h1x[0][mlp][3][lane] = 0u; h1x[1][mlp][3][lane] = 0u;
  if (lane < 4) { h1x[0][mlp][3][64 + lane] = 0u; h1x[1][mlp][3][64 + lane] = 0u; }

  // A-frag base pointers: region (n&3) of this wave's MLP, quad offset q.
  const u32x4* hq0 = ((const u32x4*)&h1x[0][mlp][0][0]) + 17 * (n & 3) + q;
  const u32x4* hq1 = ((const u32x4*)&h1x[1][mlp][0][0]) + 17 * (n & 3) + q;

  // ---- scan state (uniform) + per-lane area ----
  const float r0 = r_ult[b];
  float r_s = r0;
  float aNow = r0, aUpd = r0, aMid = r0;   // anchors: batch k, k+1, k+2
  float area_p = 0.f;
  const int sj = lane;                     // lane = step-PAIR index (2sj,2sj+1)
  const float jjA = 2.0f * (float)sj - 63.5f;
  const float jjB = jjA + 1.0f;

  // ---- prologue: layer-1 one-eval for batch 0 -> slot 0, anchor r0 ----
  STAGE3M(TSTEP * 63.5f, 0, r0)
  __syncthreads();

  // ---- main loop: body k: scan batch k, MFMA batch k+1, STAGE3 batch k+2
#pragma unroll 1
  for (int k = -1; k < NBODY; ++k) {
    const int sl = k & 1;        // msum slot (batch k); h1 write slot (batch k+2)
    const int so = sl ^ 1;       // h1 read slot (batch k+1); msum write slot

    // --- LDS reads issued early ---
    f32x4 m0 = *(const f32x4*)&msum[sl][0][0];
    f32x4 m1 = *(const f32x4*)&msum[sl][1][0];
    f32x4 m2 = *(const f32x4*)&msum[sl][2][0];
    f32x4 m3 = *(const f32x4*)&msum[sl][3][0];
    const int u0 = k < 0 ? 0 : 128 * k;
    const float2 mw2 = *(const float2*)&meanw[u0 + 2 * sj];
    const u32x4* hq = so ? hq1 : hq0;
    u32x4 af0 = hq[0], af1 = hq[4], af2 = hq[8], af3 = hq[12];

    // --- MFMA batch k+1 (matrix pipe) ---
    f32x4 ac0 = {0,0,0,0}, ac1 = {0,0,0,0}, ac2 = {0,0,0,0}, ac3 = {0,0,0,0};
    MFMA1(ac0, af0, b_0_0) MFMA1(ac1, af0, b_0_1) MFMA1(ac2, af0, b_0_2) MFMA1(ac3, af0, b_0_3)
    MFMA1(ac0, af1, b_1_0) MFMA1(ac1, af1, b_1_1) MFMA1(ac2, af1, b_1_2) MFMA1(ac3, af1, b_1_3)
    MFMA1(ac0, af2, b_2_0) MFMA1(ac1, af2, b_2_1) MFMA1(ac2, af2, b_2_2) MFMA1(ac3, af2, b_2_3)
    MFMA1(ac0, af3, b_3_0) MFMA1(ac1, af3, b_3_1) MFMA1(ac2, af3, b_3_2) MFMA1(ac3, af3, b_3_3)

    // --- STAGE3 batch k+2 (anchor aMid from previous rotation) ---
    STAGE3M(TSTEP * ((float)(128 * (k + 2)) + 63.5f), sl, aMid)

    // --- affine scan for batch k (lane sj = steps 128k+2sj, 128k+2sj+1) ---
    {
      float MV = (m0[0] + m1[0]) + b3mu;
      float MR = (m0[1] + m1[1]) * TSC_INV;
      float MT = (m0[2] + m1[2]) * TSCT_INV;
      float ZV = (m2[0] + m3[0]) + b3si;
      float ZR = (m2[1] + m3[1]) * TSC_INV;
      float ZT = (m2[2] + m3[2]) * TSCT_INV;
      // softplus at z_mid + 2nd-order Taylor in the time offset
      float e_ = __expf(-fabsf(ZV));
      float sp = fmaxf(ZV, 0.f) + __logf(1.0f + e_) + 1e-5f;
      float inv = fast_rcp(1.0f + e_);
      float sgm = ZV > 0.f ? inv : 1.0f - inv;
      float hcv = 0.5f * sgm * (1.0f - sgm);
      // step A coefficients
      float dztA = jjA * ZT;
      float sigA = __builtin_fmaf(2.0f * hcv, dztA, sgm);
      float spA  = __builtin_fmaf(__builtin_fmaf(hcv, dztA, sgm), dztA, sp);
      float sZRA = sigA * ZR;
      float betaA = __builtin_fmaf(sZRA, mw2.x, __builtin_fmaf(MR, DTF, 1.0f));
      float amA = __builtin_fmaf(jjA, MT, __builtin_fmaf(-aNow, MR, MV));
      float asA = __builtin_fmaf(-aNow, sZRA, spA);
      float alphaA = __builtin_fmaf(amA, DTF, asA * mw2.x);
      // step B coefficients
      float dztB = jjB * ZT;
      float sigB = __builtin_fmaf(2.0f * hcv, dztB, sgm);
      float spB  = __builtin_fmaf(__builtin_fmaf(hcv, dztB, sgm), dztB, sp);
      float sZRB = sigB * ZR;
      float betaB = __builtin_fmaf(sZRB, mw2.y, __builtin_fmaf(MR, DTF, 1.0f));
      float amB = __builtin_fmaf(jjB, MT, __builtin_fmaf(-aNow, MR, MV));
      float asB = __builtin_fmaf(-aNow, sZRB, spB);
      float alphaB = __builtin_fmaf(amB, DTF, asB * mw2.y);
      // pair compose: step A then step B
      float B = betaB * betaA;
      float A = __builtin_fmaf(betaB, alphaA, alphaB);
      // inclusive affine prefix scan over 64 lanes (= 128 steps):
      {
        float Bs = dpp_mov<0x111, 0xf>(B, 1.0f), As = dpp_mov<0x111, 0xf>(A, 0.0f);
        A = __builtin_fmaf(B, As, A); B = B * Bs;
        Bs = dpp_mov<0x112, 0xf>(B, 1.0f); As = dpp_mov<0x112, 0xf>(A, 0.0f);
        A = __builtin_fmaf(B, As, A); B = B * Bs;
        Bs = dpp_mov<0x114, 0xf>(B, 1.0f); As = dpp_mov<0x114, 0xf>(A, 0.0f);
        A = __builtin_fmaf(B, As, A); B = B * Bs;
        Bs = dpp_mov<0x118, 0xf>(B, 1.0f); As = dpp_mov<0x118, 0xf>(A, 0.0f);
        A = __builtin_fmaf(B, As, A); B = B * Bs;
        Bs = dpp_mov<0x142, 0xa>(B, 1.0f); As = dpp_mov<0x142, 0xa>(A, 0.0f);
        A = __builtin_fmaf(B, As, A); B = B * Bs;
        Bs = dpp_mov<0x143, 0xc>(B, 1.0f); As = dpp_mov<0x143, 0xc>(A, 0.0f);
        A = __builtin_fmaf(B, As, A); B = B * Bs;
      }
      float rhoB = __builtin_fmaf(B, r_s, A);      // state after step 2sj+1
      if (k >= 0) {
        // state before this lane's pair: full-wave shfl_up by 1 (lane0 -> r_s)
        float prev = __shfl_up(rhoB, 1, 64);
        prev = sj == 0 ? r_s : prev;
        float rhoA = __builtin_fmaf(betaA, prev, alphaA);  // after step 2sj
        const int s0 = 128 * k + 2 * sj;
        float ca = s0 < NSTEPS ? rhoA * DTF : 0.f;
        float cb = (s0 + 1) < NSTEPS ? rhoB * DTF : 0.f;
        area_p += ca + cb;
        float rn = readlane_f(rhoB, 63);
        // drift-only prediction for batch k+3 (mid-step distance ~191.5)
        float aNew = __builtin_fmaf(MV, 191.5f * DTF, rn);
        r_s = rn;
        aNow = aUpd; aUpd = aMid; aMid = aNew;
      }
    }

    // --- MFMA dst -> VALU read hazard fence ---
    asm volatile("s_nop 7\n\ts_nop 7"
                 : "+v"(ac0), "+v"(ac1), "+v"(ac2), "+v"(ac3));

    // --- epilogue batch k+1: lane (q,n) handles its single column (C=q) ---
    {
      const f32x4 aq = q == 0 ? ac0 : q == 1 ? ac1 : q == 2 ? ac2 : ac3;
      float yv = aq[0] + b2E;
      float ytr = aq[1];                 // d/dr row (scaled TSC)
      float ytt = aq[2];                 // d/dt row (scaled TSC_T)
      float ev = eigen_erf_fast(yv * INV_SQRT2);
      float cv = (ev + 1.0f) * 0.5f;
      float pv = yv * cv * w3E;
      float phv = PHI_C * __expf(-0.5f * yv * yv);
      float g2p = __builtin_fmaf(yv, phv, cv) * w3E;
      float pr = g2p * ytr;
      float pt = g2p * ytt;
      pv = dpp_reduce63(pv);
      pr = dpp_reduce63(pr);
      pt = dpp_reduce63(pt);
      if (lane == 63) {
        *(f32x4*)&msum[so][wv][0] = (f32x4){pv, pr, pt, 0.f};
      }
    }
    __syncthreads();  // publish msum[so] (batch k+1) + h1x[sl] (batch k+2)
  }

  // area: lanes hold per-pair partials
  float area = area_p;
  area += __shfl_xor(area, 1, 64);
  area += __shfl_xor(area, 2, 64);
  area += __shfl_xor(area, 4, 64);
  area += __shfl_xor(area, 8, 64);
  area += __shfl_xor(area, 16, 64);
  area += __shfl_xor(area, 32, 64);

  if (t < NMAT) {
    float mx = mats[0];
#pragma unroll
    for (int i = 1; i < NMAT; ++i) mx = fmaxf(mx, mats[i]);
    const float mm = mats[t];
    const float frac = mm / (mx + 1e-12f);
    out[b * NMAT + t] = (area * frac) / (mm + 1e-12f);
  }
}

extern "C" void kernel_launch(void* const* d_in, const int* in_sizes, int n_in,
                              void* d_out, int out_size, void* d_ws, size_t ws_size,
                              hipStream_t stream) {
  (void)in_sizes; (void)n_in; (void)ws_size; (void)out_size;
  const float* X      = (const float*)d_in[0];
  const float* r_ult  = (const float*)d_in[1];
  const float* mats   = (const float*)d_in[2];
  const float* Wp     = (const float*)d_in[3];
  const float* bp     = (const float*)d_in[4];
  const float* ln_g   = (const float*)d_in[5];
  const float* ln_b   = (const float*)d_in[6];
  const float* muW1   = (const float*)d_in[7];
  const float* mub1   = (const float*)d_in[8];
  const float* muW2   = (const float*)d_in[9];
  const float* mub2   = (const float*)d_in[10];
  const float* muW3   = (const float*)d_in[11];
  const float* mub3   = (const float*)d_in[12];
  const float* siW1   = (const float*)d_in[13];
  const float* sib1   = (const float*)d_in[14];
  const float* siW2   = (const float*)d_in[15];
  const float* sib2   = (const float*)d_in[16];
  const float* siW3   = (const float*)d_in[17];
  const float* sib3   = (const float*)d_in[18];
  float* ws = (float*)d_ws;   // 64*2520*4 = 645,120 bytes

  hipLaunchKernelGGL(vasicek_phase1_meandw,
                     dim3(NB * NSTEPS / 4), dim3(256), 0, stream, ws);
  hipLaunchKernelGGL(vasicek_phase2_scan,
                     dim3(NB), dim3(256), 0, stream,
                     X, r_ult, mats, Wp, bp, ln_g, ln_b,
                     muW1, mub1, muW2, mub2, muW3, mub3,
                     siW1, sib1, siW2, sib2, siW3, sib3,
                     ws, (float*)d_out);
}

// Round 16
// 251.792 us; speedup vs baseline: 12.0051x; 1.0202x over previous
//
#include <hip/hip_runtime.h>
#include <stdint.h>

// ModeloNeuralVasicek — two-phase mean-recursion.
// Round 32: R31 fit: p2 = F + 0.7us*bodies with F~90us preamble-fixed;
// p1 ~120us vs ~60us issue floor (incl. redundant per-thread key threefry).
// Changes (scan structure byte-identical to R31, absmax-verified):
//  (1) p1 key threefry on the SCALAR pipe: s,b readfirstlane'd -> s_ ops
//      (shift-or rotate); frees ~15% of VALU issue.
//  (2) p1 reduce via DPP chain (VALU) instead of ds shfl_xor; store lane 63;
//      2^-8 folded into NRM_C (exact scaling, bit-identical).
//  (3) p2 c1 mat-vec: 4 accumulators + unroll 8 -> batched loads, kills the
//      192-deep latency chain (largest identified chunk of F).

#define NSTEPS 2520
#define NB 64
#define NT 256
#define NQ 256
#define NMAT 7
#define NBODY 20
#define MWPAD 2560

typedef uint32_t u32x4 __attribute__((ext_vector_type(4)));
typedef float f32x4 __attribute__((ext_vector_type(4)));

// vector 1-op rotate (VALU): alignbit(v,v,32-n)
__device__ __forceinline__ uint32_t rotl32(uint32_t v, int n) {
  return __builtin_amdgcn_alignbit(v, v, (uint32_t)(32 - n));
}
// scalar-friendly rotate: uniform inputs compile to s_lshl/s_lshr/s_or
__device__ __forceinline__ uint32_t rotl32s(uint32_t v, int n) {
  return (v << n) | (v >> (32 - n));
}

// vector threefry round macro (used by phase1 normal loops)
#define R4(a,b,c,d) \
  x0 += x1; x1 = rotl32(x1,(a)); x1 ^= x0; \
  x0 += x1; x1 = rotl32(x1,(b)); x1 ^= x0; \
  x0 += x1; x1 = rotl32(x1,(c)); x1 ^= x0; \
  x0 += x1; x1 = rotl32(x1,(d)); x1 ^= x0;

// Threefry-2x32, 20 rounds — matches jax._src.prng.threefry2x32 exactly.
// Scalar-friendly form: with uniform inputs the whole body scalarizes.
__device__ __forceinline__ void tf2x32(uint32_t k0, uint32_t k1,
                                       uint32_t x0, uint32_t x1,
                                       uint32_t& o0, uint32_t& o1) {
  const uint32_t k2 = k0 ^ k1 ^ 0x1BD11BDAu;
  x0 += k0; x1 += k1;
#define R4S(a,b,c,d) \
  x0 += x1; x1 = rotl32s(x1,(a)); x1 ^= x0; \
  x0 += x1; x1 = rotl32s(x1,(b)); x1 ^= x0; \
  x0 += x1; x1 = rotl32s(x1,(c)); x1 ^= x0; \
  x0 += x1; x1 = rotl32s(x1,(d)); x1 ^= x0;
  R4S(13,15,26,6)  x0 += k1; x1 += k2 + 1u;
  R4S(17,29,16,24) x0 += k2; x1 += k0 + 2u;
  R4S(13,15,26,6)  x0 += k0; x1 += k1 + 3u;
  R4S(17,29,16,24) x0 += k1; x1 += k2 + 4u;
  R4S(13,15,26,6)  x0 += k2; x1 += k0 + 5u;
#undef R4S
  o0 = x0; o1 = x1;
}

// fast reciprocal: v_rcp + one Newton step (~1e-7 rel)
__device__ __forceinline__ float fast_rcp(float q) {
  float r = __builtin_amdgcn_rcpf(q);
  r = __builtin_fmaf(r, __builtin_fmaf(-q, r, 1.0f), r);
  return r;
}

// Eigen/XLA generic_fast_tanh_float (context aggregator only).
__device__ __forceinline__ float eigen_tanh(float a_x) {
  float x = fminf(fmaxf(a_x, -7.90531110763549805f), 7.90531110763549805f);
  float x2 = x * x;
  float p = __builtin_fmaf(x2, -2.76076847742355e-16f, 2.00018790482477e-13f);
  p = __builtin_fmaf(x2, p, -8.60467152213735e-11f);
  p = __builtin_fmaf(x2, p, 5.12229709037114e-08f);
  p = __builtin_fmaf(x2, p, 1.48572235717979e-05f);
  p = __builtin_fmaf(x2, p, 6.37261928875436e-04f);
  p = __builtin_fmaf(x2, p, 4.89352455891786e-03f);
  p = x * p;
  float q = __builtin_fmaf(x2, 1.19825839466702e-06f, 1.18534705686654e-04f);
  q = __builtin_fmaf(x2, q, 2.26843463243900e-03f);
  q = __builtin_fmaf(x2, q, 4.89352518554385e-03f);
  float rr = p / q;
  return (fabsf(a_x) < 0.0004f) ? a_x : rr;
}

// Eigen/XLA erf polynomial with rcp-division.
__device__ __forceinline__ float eigen_erf_fast(float a_x) {
  float x = fminf(fmaxf(a_x, -4.0f), 4.0f);
  float x2 = x * x;
  float p = __builtin_fmaf(x2, -2.72614225801306e-10f, 2.77068142495902e-08f);
  p = __builtin_fmaf(x2, p, -2.10102402082508e-06f);
  p = __builtin_fmaf(x2, p, -5.69250639462346e-05f);
  p = __builtin_fmaf(x2, p, -7.34990630326855e-04f);
  p = __builtin_fmaf(x2, p, -2.95459980854025e-03f);
  p = __builtin_fmaf(x2, p, -1.60960333262415e-02f);
  p = x * p;
  float q = __builtin_fmaf(x2, -1.45660718464996e-05f, -2.13374055278905e-04f);
  q = __builtin_fmaf(x2, q, -1.68282697438203e-03f);
  q = __builtin_fmaf(x2, q, -7.37332916720468e-03f);
  q = __builtin_fmaf(x2, q, -1.42647390514189e-02f);
  return p * fast_rcp(q);
}

__device__ __forceinline__ uint16_t f32_to_f16bits(float x) {
  _Float16 hv = (_Float16)x;  // RNE
  return __builtin_bit_cast(uint16_t, hv);
}

__device__ __forceinline__ uint32_t pack_f16x2(float lo, float hi) {
  return (uint32_t)f32_to_f16bits(lo) | ((uint32_t)f32_to_f16bits(hi) << 16);
}

// DPP add: v += dpp_move(v). 0x111..0x118 row_shr; 0x142/0x143 row_bcast.
template <int CTRL, int RMASK>
__device__ __forceinline__ float dpp_add(float v) {
  int x = __builtin_amdgcn_update_dpp(0, __float_as_int(v), CTRL, RMASK, 0xf, true);
  return v + __int_as_float(x);
}

// full-wave sum -> lane 63 (validated chain)
__device__ __forceinline__ float dpp_reduce63(float p) {
  p = dpp_add<0x111, 0xf>(p);
  p = dpp_add<0x112, 0xf>(p);
  p = dpp_add<0x114, 0xf>(p);
  p = dpp_add<0x118, 0xf>(p);
  p = dpp_add<0x142, 0xa>(p);
  p = dpp_add<0x143, 0xc>(p);
  return p;
}

// DPP move with explicit identity; RMASK gates receiving rows (others keep
// OLD); bound_ctrl=false keeps OLD for no-src lanes.
template <int CTRL, int RMASK>
__device__ __forceinline__ float dpp_mov(float v, float old) {
  int x = __builtin_amdgcn_update_dpp(__float_as_int(old), __float_as_int(v),
                                      CTRL, RMASK, 0xf, false);
  return __int_as_float(x);
}

__device__ __forceinline__ float readlane_f(float v, int l) {
  return __int_as_float(__builtin_amdgcn_readlane(__float_as_int(v), l));
}

#define DTF  0.00396825396825396826f
#define SQDT 0.06299407883487120442f
#define TSTEP (1.0f / 2519.0f)
#define TSC      64.0f
#define TSC_INV  0.015625f
#define TSC_T    1024.0f
#define TSCT_INV 0.0009765625f
#define INV_SQRT2 0.7071067811865475f
#define PHI_C     0.3989422804014327f
#define NEG_LN2  -0.69314718055994530942f
#define LG2_W5   -7.2134752044448170368f
// sqrt(2)*SQDT/256 — 2^-8 folded in exactly (pure exponent shift)
#define NRM_C256 3.4799640873972965e-4f

// ---------------- Phase 1: mean_dW[b][s] — fully parallel ----------------
__global__ __launch_bounds__(256)
void vasicek_phase1_meandw(float* __restrict__ ws) {
  const int tid = threadIdx.x;
  const int lane = tid & 63;
  const int wv = tid >> 6;
  const int wid = blockIdx.x * 4 + wv;          // 0 .. 64*2520-1
  const int b = wid / NSTEPS;
  const int s = wid - b * NSTEPS;

  // key derivation on the SCALAR pipe: s,b are wave-uniform
  const uint32_t su = (uint32_t)__builtin_amdgcn_readfirstlane(s);
  const uint32_t bu = (uint32_t)__builtin_amdgcn_readfirstlane(b);
  uint32_t kA, kB;
  tf2x32(0u, 1u, 0u, su, kA, kB);               // split(key(1))[s], scalar
  const uint32_t k2 = kA ^ kB ^ 0x1BD11BDAu;
  const uint32_t x1base = bu * NQ + (uint32_t)lane + kB;  // pre-keyed x1

  const float MINVAL = -0.999999940395355224609375f;
  float sum = 0.f;
#pragma unroll
  for (int i = 0; i < 4; ++i) {
    uint32_t x0 = kA, x1 = x1base + (uint32_t)(i * 64);
    R4(13,15,26,6)  x0 += kB; x1 += k2 + 1u;
    R4(17,29,16,24) x0 += k2; x1 += kA + 2u;
    R4(13,15,26,6)  x0 += kA; x1 += kB + 3u;
    R4(17,29,16,24) x0 += kB; x1 += k2 + 4u;
    R4(13,15,26,6)  x0 += k2; x1 += kA + 5u;
    const uint32_t bits = x0 ^ x1;

    uint32_t fb = (bits >> 9) | 0x3F800000u;
    float u = __builtin_fmaf(__uint_as_float(fb) - 1.0f, 2.0f, MINVAL);
    u = fmaxf(u, MINVAL);
    float omsq = __builtin_fmaf(u, -u, 1.0f);
    float lg = __builtin_amdgcn_logf(omsq);
    float wc = __builtin_fmaf(lg, NEG_LN2, -2.5f);
    float p = 2.81022636e-08f;
    p = __builtin_fmaf(p, wc, 3.43273939e-07f);
    p = __builtin_fmaf(p, wc, -3.5233877e-06f);
    p = __builtin_fmaf(p, wc, -4.39150654e-06f);
    p = __builtin_fmaf(p, wc, 0.00021858087f);
    p = __builtin_fmaf(p, wc, -0.00125372503f);
    p = __builtin_fmaf(p, wc, -0.00417768164f);
    p = __builtin_fmaf(p, wc, 0.246640727f);
    p = __builtin_fmaf(p, wc, 1.50140941f);
    if (__ballot(lg <= LG2_W5)) {                      // rare (~0.3% lanes)
      float w = lg * NEG_LN2;
      float wsr = sqrtf(w) - 3.0f;
      float pr = -0.000200214257f;
      pr = __builtin_fmaf(pr, wsr, 0.000100950558f);
      pr = __builtin_fmaf(pr, wsr, 0.00134934322f);
      pr = __builtin_fmaf(pr, wsr, -0.00367342844f);
      pr = __builtin_fmaf(pr, wsr, 0.00573950773f);
      pr = __builtin_fmaf(pr, wsr, -0.0076224613f);
      pr = __builtin_fmaf(pr, wsr, 0.00943887047f);
      pr = __builtin_fmaf(pr, wsr, 1.00167406f);
      pr = __builtin_fmaf(pr, wsr, 2.83297682f);
      p = (lg <= LG2_W5) ? pr : p;
    }
    sum = __builtin_fmaf(p * u, NRM_C256, sum);  // 1/256 folded (exact 2^-8)
  }
  sum = dpp_reduce63(sum);            // VALU-pipe reduce; total in lane 63
  if (lane == 63) ws[b * NSTEPS + s] = sum;
}

// ---- B-fragment machinery, k-PERMUTED (unchanged from R20/R23/R26):
// B dword d of K-chunk T (lane q,n) holds W2 rows (16T+4q+d, 64+16T+4q+d)
// at column 16*(4*half+C) + n, f16x2 packed.
#define BDECL(T, C) u32x4 b_##T##_##C;
#define BINIT(T, C) { \
  const int col_ = 16 * (4 * half + (C)) + n; \
  const int r0_ = 16 * (T) + 4 * q; \
  b_##T##_##C = (u32x4){ \
    pack_f16x2(W2src[(r0_ + 0) * 128 + col_], W2src[(r0_ + 64) * 128 + col_]), \
    pack_f16x2(W2src[(r0_ + 1) * 128 + col_], W2src[(r0_ + 65) * 128 + col_]), \
    pack_f16x2(W2src[(r0_ + 2) * 128 + col_], W2src[(r0_ + 66) * 128 + col_]), \
    pack_f16x2(W2src[(r0_ + 3) * 128 + col_], W2src[(r0_ + 67) * 128 + col_])}; \
  asm volatile("" : "+a"(b_##T##_##C)); /* pin in AGPR quad */ \
}
#define MFMA1(ACC, AF, BF) \
  asm("v_mfma_f32_16x16x32_f16 %0, %1, %2, %0" : "+v"(ACC) : "v"(AF), "a"(BF));

// one-eval layer-1 for a batch: anchor A_, mid-time TV; writes regions
// 0=val, 1=d/dr*64, 2=d/dt_j*1024 (region 3 pre-zeroed).
#define STAGE3M(TV, SLOT, A_) { \
  float pre_ = __builtin_fmaf((TV), w11, __builtin_fmaf((A_), w10, c1)); \
  float e_ = eigen_erf_fast(pre_ * INV_SQRT2); \
  float cg_ = (e_ + 1.0f) * 0.5f; \
  float v_ = pre_ * cg_; \
  float ph_ = PHI_C * __expf(-0.5f * pre_ * pre_); \
  float gp_ = __builtin_fmaf(pre_, ph_, cg_); \
  ((uint16_t*)&h1x[SLOT][mlp][0][0])[2 * lane + half] = f32_to_f16bits(v_); \
  ((uint16_t*)&h1x[SLOT][mlp][1][0])[2 * lane + half] = f32_to_f16bits(gp_ * w10S); \
  ((uint16_t*)&h1x[SLOT][mlp][2][0])[2 * lane + half] = f32_to_f16bits(gp_ * w11T); \
}

// ---------------- Phase 2: scan, 64 blocks x 256 ---------------------------
__global__
__attribute__((amdgpu_flat_work_group_size(256, 256)))
__attribute__((amdgpu_waves_per_eu(1, 1)))
void vasicek_phase2_scan(
    const float* __restrict__ X, const float* __restrict__ r_ult,
    const float* __restrict__ mats,
    const float* __restrict__ Wp, const float* __restrict__ bp,
    const float* __restrict__ ln_g, const float* __restrict__ ln_b,
    const float* __restrict__ muW1, const float* __restrict__ mub1,
    const float* __restrict__ muW2, const float* __restrict__ mub2,
    const float* __restrict__ muW3, const float* __restrict__ mub3,
    const float* __restrict__ siW1, const float* __restrict__ sib1,
    const float* __restrict__ siW2, const float* __restrict__ sib2,
    const float* __restrict__ siW3, const float* __restrict__ sib3,
    const float* __restrict__ ws, float* __restrict__ out) {
  // [slot][mlp][region: 0=val,1=dr,2=dt,3=zero][68 dw] (stride 272B==16 mod 128)
  __shared__ __align__(16) uint32_t h1x[2][2][4][68];
  __shared__ __align__(16) float meanw[MWPAD];
  __shared__ float part[256];
  __shared__ float mbuf[64];
  __shared__ float ctx_lds[192];
  __shared__ __align__(16) float msum[2][4][4];   // [slot][wave][PV,PR,PT,pad]

  const int t = threadIdx.x;
  const int b = blockIdx.x;
  const int lane = t & 63;
  const int wv = t >> 6;

  for (int i = t; i < MWPAD; i += 256)
    meanw[i] = i < NSTEPS ? ws[b * NSTEPS + i] : 0.f;

  // ---- context aggregator (all 256 threads, one T-row each) ----
  float h[64];
  {
    float x0 = X[(b * NT + t) * 2 + 0];
    float x1 = X[(b * NT + t) * 2 + 1];
    float s = 0.f;
#pragma unroll
    for (int c = 0; c < 64; ++c) {
      float pre = __builtin_fmaf(x1, Wp[64 + c], x0 * Wp[c]) + bp[c];
      h[c] = eigen_tanh(pre);
      s += h[c];
    }
    float m = s * 0.015625f;
    float vs = 0.f;
#pragma unroll
    for (int c = 0; c < 64; ++c) { float d = h[c] - m; vs = __builtin_fmaf(d, d, vs); }
    float den = sqrtf(vs * 0.015625f + 1e-5f);
#pragma unroll
    for (int c = 0; c < 64; ++c)
      h[c] = ((h[c] - m) / den) * ln_g[c] + ln_b[c];
  }
#pragma unroll
  for (int c = 0; c < 64; ++c) {
    float v = h[c];
    v += __shfl_xor(v, 32, 64); v += __shfl_xor(v, 16, 64);
    v += __shfl_xor(v, 8, 64);  v += __shfl_xor(v, 4, 64);
    v += __shfl_xor(v, 2, 64);  v += __shfl_xor(v, 1, 64);
    if (lane == 0) part[wv * 64 + c] = v;
  }
  __syncthreads();
  if (t < 64) {
    float m = ((part[t] + part[64 + t]) + (part[128 + t] + part[192 + t])) * (1.0f / 256.0f);
    mbuf[t] = m;
    ctx_lds[t] = m;
  }
  __syncthreads();
#pragma unroll
  for (int c = 0; c < 64; ++c) {
    float d = h[c] - mbuf[c];
    float v = d * d;
    v += __shfl_xor(v, 32, 64); v += __shfl_xor(v, 16, 64);
    v += __shfl_xor(v, 8, 64);  v += __shfl_xor(v, 4, 64);
    v += __shfl_xor(v, 2, 64);  v += __shfl_xor(v, 1, 64);
    if (lane == 0) part[wv * 64 + c] = v;
  }
  if (t == 255) {
#pragma unroll
    for (int c = 0; c < 64; ++c) ctx_lds[128 + c] = h[c];
  }
  __syncthreads();
  if (t < 64) {
    float vs = (part[t] + part[64 + t]) + (part[128 + t] + part[192 + t]);
    ctx_lds[64 + t] = sqrtf(vs / 255.0f);
  }
  __syncthreads();

  // ---- per-wave roles: mlp = wv>>1 (0=mu,1=si), half = wv&1 ----
  const int mlp = wv >> 1;
  const int half = wv & 1;
  const int jH = 64 * half + lane;            // layer-1 element ownership
  const float* W1 = mlp == 0 ? muW1 : siW1;
  const float* W2src = mlp == 0 ? muW2 : siW2;
  // c1 mat-vec: 4 independent accumulators, batched loads (ILP)
  float c10 = (mlp == 0 ? mub1 : sib1)[jH];
  float c11 = 0.f, c12 = 0.f, c13 = 0.f;
#pragma unroll 8
  for (int c = 0; c < 192; c += 4) {
    c10 = __builtin_fmaf(ctx_lds[c],     W1[(2 + c) * 128 + jH], c10);
    c11 = __builtin_fmaf(ctx_lds[c + 1], W1[(3 + c) * 128 + jH], c11);
    c12 = __builtin_fmaf(ctx_lds[c + 2], W1[(4 + c) * 128 + jH], c12);
    c13 = __builtin_fmaf(ctx_lds[c + 3], W1[(5 + c) * 128 + jH], c13);
  }
  const float c1 = (c10 + c11) + (c12 + c13);
  const float w10 = W1[jH], w11 = W1[128 + jH];
  const float w10S = w10 * TSC;
  const float w11T = w11 * (TSTEP * TSC_T);
  const float b3mu = mub3[0], b3si = sib3[0];

  const int q = lane >> 4, n = lane & 15;

  // per-lane epilogue constants: this lane's single column (chunk C = q)
  const float* b2p = mlp == 0 ? mub2 : sib2;
  const float* w3p = mlp == 0 ? muW3 : siW3;
  const int colE = 64 * half + 16 * q + n;
  const float b2E = b2p[colE], w3E = w3p[colE];

  // this wave's 4 col-tiles of its W2 -> 16 AGPR quads (one-time; pinned)
  BDECL(0,0) BDECL(0,1) BDECL(0,2) BDECL(0,3)
  BDECL(1,0) BDECL(1,1) BDECL(1,2) BDECL(1,3)
  BDECL(2,0) BDECL(2,1) BDECL(2,2) BDECL(2,3)
  BDECL(3,0) BDECL(3,1) BDECL(3,2) BDECL(3,3)
  BINIT(0,0) BINIT(0,1) BINIT(0,2) BINIT(0,3)
  BINIT(1,0) BINIT(1,1) BINIT(1,2) BINIT(1,3)
  BINIT(2,0) BINIT(2,1) BINIT(2,2) BINIT(2,3)
  BINIT(3,0) BINIT(3,1) BINIT(3,2) BINIT(3,3)

  // zero region 3 (A-rows 3,7,11,15) for both slots of this wave's MLP
  h1x[0][mlp][3][lane] = 0u; h1x[1][mlp][3][lane] = 0u;
  if (lane < 4) { h1x[0][mlp][3][64 + lane] = 0u; h1x[1][mlp][3][64 + lane] = 0u; }

  // A-frag base pointers: region (n&3) of this wave's MLP, quad offset q.
  const u32x4* hq0 = ((const u32x4*)&h1x[0][mlp][0][0]) + 17 * (n & 3) + q;
  const u32x4* hq1 = ((const u32x4*)&h1x[1][mlp][0][0]) + 17 * (n & 3) + q;

  // ---- scan state (uniform) + per-lane area ----
  const float r0 = r_ult[b];
  float r_s = r0;
  float aNow = r0, aUpd = r0, aMid = r0;   // anchors: batch k, k+1, k+2
  float area_p = 0.f;
  const int sj = lane;                     // lane = step-PAIR index (2sj,2sj+1)
  const float jjA = 2.0f * (float)sj - 63.5f;
  const float jjB = jjA + 1.0f;

  // ---- prologue: layer-1 one-eval for batch 0 -> slot 0, anchor r0 ----
  STAGE3M(TSTEP * 63.5f, 0, r0)
  __syncthreads();

  // ---- main loop: body k: scan batch k, MFMA batch k+1, STAGE3 batch k+2
#pragma unroll 1
  for (int k = -1; k < NBODY; ++k) {
    const int sl = k & 1;        // msum slot (batch k); h1 write slot (batch k+2)
    const int so = sl ^ 1;       // h1 read slot (batch k+1); msum write slot

    // --- LDS reads issued early ---
    f32x4 m0 = *(const f32x4*)&msum[sl][0][0];
    f32x4 m1 = *(const f32x4*)&msum[sl][1][0];
    f32x4 m2 = *(const f32x4*)&msum[sl][2][0];
    f32x4 m3 = *(const f32x4*)&msum[sl][3][0];
    const int u0 = k < 0 ? 0 : 128 * k;
    const float2 mw2 = *(const float2*)&meanw[u0 + 2 * sj];
    const u32x4* hq = so ? hq1 : hq0;
    u32x4 af0 = hq[0], af1 = hq[4], af2 = hq[8], af3 = hq[12];

    // --- MFMA batch k+1 (matrix pipe) ---
    f32x4 ac0 = {0,0,0,0}, ac1 = {0,0,0,0}, ac2 = {0,0,0,0}, ac3 = {0,0,0,0};
    MFMA1(ac0, af0, b_0_0) MFMA1(ac1, af0, b_0_1) MFMA1(ac2, af0, b_0_2) MFMA1(ac3, af0, b_0_3)
    MFMA1(ac0, af1, b_1_0) MFMA1(ac1, af1, b_1_1) MFMA1(ac2, af1, b_1_2) MFMA1(ac3, af1, b_1_3)
    MFMA1(ac0, af2, b_2_0) MFMA1(ac1, af2, b_2_1) MFMA1(ac2, af2, b_2_2) MFMA1(ac3, af2, b_2_3)
    MFMA1(ac0, af3, b_3_0) MFMA1(ac1, af3, b_3_1) MFMA1(ac2, af3, b_3_2) MFMA1(ac3, af3, b_3_3)

    // --- STAGE3 batch k+2 (anchor aMid from previous rotation) ---
    STAGE3M(TSTEP * ((float)(128 * (k + 2)) + 63.5f), sl, aMid)

    // --- affine scan for batch k (lane sj = steps 128k+2sj, 128k+2sj+1) ---
    {
      float MV = (m0[0] + m1[0]) + b3mu;
      float MR = (m0[1] + m1[1]) * TSC_INV;
      float MT = (m0[2] + m1[2]) * TSCT_INV;
      float ZV = (m2[0] + m3[0]) + b3si;
      float ZR = (m2[1] + m3[1]) * TSC_INV;
      float ZT = (m2[2] + m3[2]) * TSCT_INV;
      // softplus at z_mid + 2nd-order Taylor in the time offset
      float e_ = __expf(-fabsf(ZV));
      float sp = fmaxf(ZV, 0.f) + __logf(1.0f + e_) + 1e-5f;
      float inv = fast_rcp(1.0f + e_);
      float sgm = ZV > 0.f ? inv : 1.0f - inv;
      float hcv = 0.5f * sgm * (1.0f - sgm);
      // step A coefficients
      float dztA = jjA * ZT;
      float sigA = __builtin_fmaf(2.0f * hcv, dztA, sgm);
      float spA  = __builtin_fmaf(__builtin_fmaf(hcv, dztA, sgm), dztA, sp);
      float sZRA = sigA * ZR;
      float betaA = __builtin_fmaf(sZRA, mw2.x, __builtin_fmaf(MR, DTF, 1.0f));
      float amA = __builtin_fmaf(jjA, MT, __builtin_fmaf(-aNow, MR, MV));
      float asA = __builtin_fmaf(-aNow, sZRA, spA);
      float alphaA = __builtin_fmaf(amA, DTF, asA * mw2.x);
      // step B coefficients
      float dztB = jjB * ZT;
      float sigB = __builtin_fmaf(2.0f * hcv, dztB, sgm);
      float spB  = __builtin_fmaf(__builtin_fmaf(hcv, dztB, sgm), dztB, sp);
      float sZRB = sigB * ZR;
      float betaB = __builtin_fmaf(sZRB, mw2.y, __builtin_fmaf(MR, DTF, 1.0f));
      float amB = __builtin_fmaf(jjB, MT, __builtin_fmaf(-aNow, MR, MV));
      float asB = __builtin_fmaf(-aNow, sZRB, spB);
      float alphaB = __builtin_fmaf(amB, DTF, asB * mw2.y);
      // pair compose: step A then step B
      float B = betaB * betaA;
      float A = __builtin_fmaf(betaB, alphaA, alphaB);
      // inclusive affine prefix scan over 64 lanes (= 128 steps):
      {
        float Bs = dpp_mov<0x111, 0xf>(B, 1.0f), As = dpp_mov<0x111, 0xf>(A, 0.0f);
        A = __builtin_fmaf(B, As, A); B = B * Bs;
        Bs = dpp_mov<0x112, 0xf>(B, 1.0f); As = dpp_mov<0x112, 0xf>(A, 0.0f);
        A = __builtin_fmaf(B, As, A); B = B * Bs;
        Bs = dpp_mov<0x114, 0xf>(B, 1.0f); As = dpp_mov<0x114, 0xf>(A, 0.0f);
        A = __builtin_fmaf(B, As, A); B = B * Bs;
        Bs = dpp_mov<0x118, 0xf>(B, 1.0f); As = dpp_mov<0x118, 0xf>(A, 0.0f);
        A = __builtin_fmaf(B, As, A); B = B * Bs;
        Bs = dpp_mov<0x142, 0xa>(B, 1.0f); As = dpp_mov<0x142, 0xa>(A, 0.0f);
        A = __builtin_fmaf(B, As, A); B = B * Bs;
        Bs = dpp_mov<0x143, 0xc>(B, 1.0f); As = dpp_mov<0x143, 0xc>(A, 0.0f);
        A = __builtin_fmaf(B, As, A); B = B * Bs;
      }
      float rhoB = __builtin_fmaf(B, r_s, A);      // state after step 2sj+1
      if (k >= 0) {
        // state before this lane's pair: full-wave shfl_up by 1 (lane0 -> r_s)
        float prev = __shfl_up(rhoB, 1, 64);
        prev = sj == 0 ? r_s : prev;
        float rhoA = __builtin_fmaf(betaA, prev, alphaA);  // after step 2sj
        const int s0 = 128 * k + 2 * sj;
        float ca = s0 < NSTEPS ? rhoA * DTF : 0.f;
        float cb = (s0 + 1) < NSTEPS ? rhoB * DTF : 0.f;
        area_p += ca + cb;
        float rn = readlane_f(rhoB, 63);
        // drift-only prediction for batch k+3 (mid-step distance ~191.5)
        float aNew = __builtin_fmaf(MV, 191.5f * DTF, rn);
        r_s = rn;
        aNow = aUpd; aUpd = aMid; aMid = aNew;
      }
    }

    // --- MFMA dst -> VALU read hazard fence ---
    asm volatile("s_nop 7\n\ts_nop 7"
                 : "+v"(ac0), "+v"(ac1), "+v"(ac2), "+v"(ac3));

    // --- epilogue batch k+1: lane (q,n) handles its single column (C=q) ---
    {
      const f32x4 aq = q == 0 ? ac0 : q == 1 ? ac1 : q == 2 ? ac2 : ac3;
      float yv = aq[0] + b2E;
      float ytr = aq[1];                 // d/dr row (scaled TSC)
      float ytt = aq[2];                 // d/dt row (scaled TSC_T)
      float ev = eigen_erf_fast(yv * INV_SQRT2);
      float cv = (ev + 1.0f) * 0.5f;
      float pv = yv * cv * w3E;
      float phv = PHI_C * __expf(-0.5f * yv * yv);
      float g2p = __builtin_fmaf(yv, phv, cv) * w3E;
      float pr = g2p * ytr;
      float pt = g2p * ytt;
      pv = dpp_reduce63(pv);
      pr = dpp_reduce63(pr);
      pt = dpp_reduce63(pt);
      if (lane == 63) {
        *(f32x4*)&msum[so][wv][0] = (f32x4){pv, pr, pt, 0.f};
      }
    }
    __syncthreads();  // publish msum[so] (batch k+1) + h1x[sl] (batch k+2)
  }

  // area: lanes hold per-pair partials
  float area = area_p;
  area += __shfl_xor(area, 1, 64);
  area += __shfl_xor(area, 2, 64);
  area += __shfl_xor(area, 4, 64);
  area += __shfl_xor(area, 8, 64);
  area += __shfl_xor(area, 16, 64);
  area += __shfl_xor(area, 32, 64);

  if (t < NMAT) {
    float mx = mats[0];
#pragma unroll
    for (int i = 1; i < NMAT; ++i) mx = fmaxf(mx, mats[i]);
    const float mm = mats[t];
    const float frac = mm / (mx + 1e-12f);
    out[b * NMAT + t] = (area * frac) / (mm + 1e-12f);
  }
}

extern "C" void kernel_launch(void* const* d_in, const int* in_sizes, int n_in,
                              void* d_out, int out_size, void* d_ws, size_t ws_size,
                              hipStream_t stream) {
  (void)in_sizes; (void)n_in; (void)ws_size; (void)out_size;
  const float* X      = (const float*)d_in[0];
  const float* r_ult  = (const float*)d_in[1];
  const float* mats   = (const float*)d_in[2];
  const float* Wp     = (const float*)d_in[3];
  const float* bp     = (const float*)d_in[4];
  const float* ln_g   = (const float*)d_in[5];
  const float* ln_b   = (const float*)d_in[6];
  const float* muW1   = (const float*)d_in[7];
  const float* mub1   = (const float*)d_in[8];
  const float* muW2   = (const float*)d_in[9];
  const float* mub2   = (const float*)d_in[10];
  const float* muW3   = (const float*)d_in[11];
  const float* mub3   = (const float*)d_in[12];
  const float* siW1   = (const float*)d_in[13];
  const float* sib1   = (const float*)d_in[14];
  const float* siW2   = (const float*)d_in[15];
  const float* sib2   = (const float*)d_in[16];
  const float* siW3   = (const float*)d_in[17];
  const float* sib3   = (const float*)d_in[18];
  float* ws = (float*)d_ws;   // 64*2520*4 = 645,120 bytes

  hipLaunchKernelGGL(vasicek_phase1_meandw,
                     dim3(NB * NSTEPS / 4), dim3(256), 0, stream, ws);
  hipLaunchKernelGGL(vasicek_phase2_scan,
                     dim3(NB), dim3(256), 0, stream,
                     X, r_ult, mats, Wp, bp, ln_g, ln_b,
                     muW1, mub1, muW2, mub2, muW3, mub3,
                     siW1, sib1, siW2, sib2, siW3, sib3,
                     ws, (float*)d_out);
}

// Round 17
// 227.065 us; speedup vs baseline: 13.3124x; 1.1089x over previous
//
#include <hip/hip_runtime.h>
#include <stdint.h>

// ModeloNeuralVasicek — two-phase mean-recursion.
// Round 33: ctx T-reduction off the DS pipe. R32 ledger: p2 = F(~93us) +
// 0.69/body; F is STALL not work; largest identified chunk = 1536
// __shfl_xor (DS-swizzle) per wave in the ctx aggregator, serialized on the
// per-CU LDS unit across 4 waves. Changes (rest byte-identical to R32):
//  - ONE fused pass: sum(h), sum(h^2) per channel via interleaved DPP
//    chains (VALU pipe, 4 SIMDs parallel); lane 63 writes partials.
//  - var = S2 - m*S1 (== sum((h-m)^2); margin ~3e-5 vs ~255; clamped >=0).
//  - deletes mbuf round-trip, the second h-pass, and 2 of 4 preamble
//    barriers. Phase1 byte-identical to R32 (116.2us).

#define NSTEPS 2520
#define NB 64
#define NT 256
#define NQ 256
#define NMAT 7
#define NBODY 20
#define MWPAD 2560

typedef uint32_t u32x4 __attribute__((ext_vector_type(4)));
typedef float f32x4 __attribute__((ext_vector_type(4)));

// vector 1-op rotate (VALU): alignbit(v,v,32-n)
__device__ __forceinline__ uint32_t rotl32(uint32_t v, int n) {
  return __builtin_amdgcn_alignbit(v, v, (uint32_t)(32 - n));
}
// scalar-friendly rotate: uniform inputs compile to s_lshl/s_lshr/s_or
__device__ __forceinline__ uint32_t rotl32s(uint32_t v, int n) {
  return (v << n) | (v >> (32 - n));
}

// vector threefry round macro (used by phase1 normal loops)
#define R4(a,b,c,d) \
  x0 += x1; x1 = rotl32(x1,(a)); x1 ^= x0; \
  x0 += x1; x1 = rotl32(x1,(b)); x1 ^= x0; \
  x0 += x1; x1 = rotl32(x1,(c)); x1 ^= x0; \
  x0 += x1; x1 = rotl32(x1,(d)); x1 ^= x0;

// Threefry-2x32, 20 rounds — matches jax._src.prng.threefry2x32 exactly.
// Scalar-friendly form: with uniform inputs the whole body scalarizes.
__device__ __forceinline__ void tf2x32(uint32_t k0, uint32_t k1,
                                       uint32_t x0, uint32_t x1,
                                       uint32_t& o0, uint32_t& o1) {
  const uint32_t k2 = k0 ^ k1 ^ 0x1BD11BDAu;
  x0 += k0; x1 += k1;
#define R4S(a,b,c,d) \
  x0 += x1; x1 = rotl32s(x1,(a)); x1 ^= x0; \
  x0 += x1; x1 = rotl32s(x1,(b)); x1 ^= x0; \
  x0 += x1; x1 = rotl32s(x1,(c)); x1 ^= x0; \
  x0 += x1; x1 = rotl32s(x1,(d)); x1 ^= x0;
  R4S(13,15,26,6)  x0 += k1; x1 += k2 + 1u;
  R4S(17,29,16,24) x0 += k2; x1 += k0 + 2u;
  R4S(13,15,26,6)  x0 += k0; x1 += k1 + 3u;
  R4S(17,29,16,24) x0 += k1; x1 += k2 + 4u;
  R4S(13,15,26,6)  x0 += k2; x1 += k0 + 5u;
#undef R4S
  o0 = x0; o1 = x1;
}

// fast reciprocal: v_rcp + one Newton step (~1e-7 rel)
__device__ __forceinline__ float fast_rcp(float q) {
  float r = __builtin_amdgcn_rcpf(q);
  r = __builtin_fmaf(r, __builtin_fmaf(-q, r, 1.0f), r);
  return r;
}

// Eigen/XLA generic_fast_tanh_float (context aggregator only).
__device__ __forceinline__ float eigen_tanh(float a_x) {
  float x = fminf(fmaxf(a_x, -7.90531110763549805f), 7.90531110763549805f);
  float x2 = x * x;
  float p = __builtin_fmaf(x2, -2.76076847742355e-16f, 2.00018790482477e-13f);
  p = __builtin_fmaf(x2, p, -8.60467152213735e-11f);
  p = __builtin_fmaf(x2, p, 5.12229709037114e-08f);
  p = __builtin_fmaf(x2, p, 1.48572235717979e-05f);
  p = __builtin_fmaf(x2, p, 6.37261928875436e-04f);
  p = __builtin_fmaf(x2, p, 4.89352455891786e-03f);
  p = x * p;
  float q = __builtin_fmaf(x2, 1.19825839466702e-06f, 1.18534705686654e-04f);
  q = __builtin_fmaf(x2, q, 2.26843463243900e-03f);
  q = __builtin_fmaf(x2, q, 4.89352518554385e-03f);
  float rr = p / q;
  return (fabsf(a_x) < 0.0004f) ? a_x : rr;
}

// Eigen/XLA erf polynomial with rcp-division.
__device__ __forceinline__ float eigen_erf_fast(float a_x) {
  float x = fminf(fmaxf(a_x, -4.0f), 4.0f);
  float x2 = x * x;
  float p = __builtin_fmaf(x2, -2.72614225801306e-10f, 2.77068142495902e-08f);
  p = __builtin_fmaf(x2, p, -2.10102402082508e-06f);
  p = __builtin_fmaf(x2, p, -5.69250639462346e-05f);
  p = __builtin_fmaf(x2, p, -7.34990630326855e-04f);
  p = __builtin_fmaf(x2, p, -2.95459980854025e-03f);
  p = __builtin_fmaf(x2, p, -1.60960333262415e-02f);
  p = x * p;
  float q = __builtin_fmaf(x2, -1.45660718464996e-05f, -2.13374055278905e-04f);
  q = __builtin_fmaf(x2, q, -1.68282697438203e-03f);
  q = __builtin_fmaf(x2, q, -7.37332916720468e-03f);
  q = __builtin_fmaf(x2, q, -1.42647390514189e-02f);
  return p * fast_rcp(q);
}

__device__ __forceinline__ uint16_t f32_to_f16bits(float x) {
  _Float16 hv = (_Float16)x;  // RNE
  return __builtin_bit_cast(uint16_t, hv);
}

__device__ __forceinline__ uint32_t pack_f16x2(float lo, float hi) {
  return (uint32_t)f32_to_f16bits(lo) | ((uint32_t)f32_to_f16bits(hi) << 16);
}

// DPP add: v += dpp_move(v). 0x111..0x118 row_shr; 0x142/0x143 row_bcast.
template <int CTRL, int RMASK>
__device__ __forceinline__ float dpp_add(float v) {
  int x = __builtin_amdgcn_update_dpp(0, __float_as_int(v), CTRL, RMASK, 0xf, true);
  return v + __int_as_float(x);
}

// full-wave sum -> lane 63 (validated chain)
__device__ __forceinline__ float dpp_reduce63(float p) {
  p = dpp_add<0x111, 0xf>(p);
  p = dpp_add<0x112, 0xf>(p);
  p = dpp_add<0x114, 0xf>(p);
  p = dpp_add<0x118, 0xf>(p);
  p = dpp_add<0x142, 0xa>(p);
  p = dpp_add<0x143, 0xc>(p);
  return p;
}

// dual interleaved full-wave sums -> lane 63 (ILP-2 on the VALU pipe)
__device__ __forceinline__ void dpp_reduce63_2(float& a, float& b) {
  a = dpp_add<0x111, 0xf>(a); b = dpp_add<0x111, 0xf>(b);
  a = dpp_add<0x112, 0xf>(a); b = dpp_add<0x112, 0xf>(b);
  a = dpp_add<0x114, 0xf>(a); b = dpp_add<0x114, 0xf>(b);
  a = dpp_add<0x118, 0xf>(a); b = dpp_add<0x118, 0xf>(b);
  a = dpp_add<0x142, 0xa>(a); b = dpp_add<0x142, 0xa>(b);
  a = dpp_add<0x143, 0xc>(a); b = dpp_add<0x143, 0xc>(b);
}

// DPP move with explicit identity; RMASK gates receiving rows (others keep
// OLD); bound_ctrl=false keeps OLD for no-src lanes.
template <int CTRL, int RMASK>
__device__ __forceinline__ float dpp_mov(float v, float old) {
  int x = __builtin_amdgcn_update_dpp(__float_as_int(old), __float_as_int(v),
                                      CTRL, RMASK, 0xf, false);
  return __int_as_float(x);
}

__device__ __forceinline__ float readlane_f(float v, int l) {
  return __int_as_float(__builtin_amdgcn_readlane(__float_as_int(v), l));
}

#define DTF  0.00396825396825396826f
#define SQDT 0.06299407883487120442f
#define TSTEP (1.0f / 2519.0f)
#define TSC      64.0f
#define TSC_INV  0.015625f
#define TSC_T    1024.0f
#define TSCT_INV 0.0009765625f
#define INV_SQRT2 0.7071067811865475f
#define PHI_C     0.3989422804014327f
#define NEG_LN2  -0.69314718055994530942f
#define LG2_W5   -7.2134752044448170368f
// sqrt(2)*SQDT/256 — 2^-8 folded in exactly (pure exponent shift)
#define NRM_C256 3.4799640873972965e-4f

// ---------------- Phase 1: mean_dW[b][s] — fully parallel ----------------
__global__ __launch_bounds__(256)
void vasicek_phase1_meandw(float* __restrict__ ws) {
  const int tid = threadIdx.x;
  const int lane = tid & 63;
  const int wv = tid >> 6;
  const int wid = blockIdx.x * 4 + wv;          // 0 .. 64*2520-1
  const int b = wid / NSTEPS;
  const int s = wid - b * NSTEPS;

  // key derivation on the SCALAR pipe: s,b are wave-uniform
  const uint32_t su = (uint32_t)__builtin_amdgcn_readfirstlane(s);
  const uint32_t bu = (uint32_t)__builtin_amdgcn_readfirstlane(b);
  uint32_t kA, kB;
  tf2x32(0u, 1u, 0u, su, kA, kB);               // split(key(1))[s], scalar
  const uint32_t k2 = kA ^ kB ^ 0x1BD11BDAu;
  const uint32_t x1base = bu * NQ + (uint32_t)lane + kB;  // pre-keyed x1

  const float MINVAL = -0.999999940395355224609375f;
  float sum = 0.f;
#pragma unroll
  for (int i = 0; i < 4; ++i) {
    uint32_t x0 = kA, x1 = x1base + (uint32_t)(i * 64);
    R4(13,15,26,6)  x0 += kB; x1 += k2 + 1u;
    R4(17,29,16,24) x0 += k2; x1 += kA + 2u;
    R4(13,15,26,6)  x0 += kA; x1 += kB + 3u;
    R4(17,29,16,24) x0 += kB; x1 += k2 + 4u;
    R4(13,15,26,6)  x0 += k2; x1 += kA + 5u;
    const uint32_t bits = x0 ^ x1;

    uint32_t fb = (bits >> 9) | 0x3F800000u;
    float u = __builtin_fmaf(__uint_as_float(fb) - 1.0f, 2.0f, MINVAL);
    u = fmaxf(u, MINVAL);
    float omsq = __builtin_fmaf(u, -u, 1.0f);
    float lg = __builtin_amdgcn_logf(omsq);
    float wc = __builtin_fmaf(lg, NEG_LN2, -2.5f);
    float p = 2.81022636e-08f;
    p = __builtin_fmaf(p, wc, 3.43273939e-07f);
    p = __builtin_fmaf(p, wc, -3.5233877e-06f);
    p = __builtin_fmaf(p, wc, -4.39150654e-06f);
    p = __builtin_fmaf(p, wc, 0.00021858087f);
    p = __builtin_fmaf(p, wc, -0.00125372503f);
    p = __builtin_fmaf(p, wc, -0.00417768164f);
    p = __builtin_fmaf(p, wc, 0.246640727f);
    p = __builtin_fmaf(p, wc, 1.50140941f);
    if (__ballot(lg <= LG2_W5)) {                      // rare (~0.3% lanes)
      float w = lg * NEG_LN2;
      float wsr = sqrtf(w) - 3.0f;
      float pr = -0.000200214257f;
      pr = __builtin_fmaf(pr, wsr, 0.000100950558f);
      pr = __builtin_fmaf(pr, wsr, 0.00134934322f);
      pr = __builtin_fmaf(pr, wsr, -0.00367342844f);
      pr = __builtin_fmaf(pr, wsr, 0.00573950773f);
      pr = __builtin_fmaf(pr, wsr, -0.0076224613f);
      pr = __builtin_fmaf(pr, wsr, 0.00943887047f);
      pr = __builtin_fmaf(pr, wsr, 1.00167406f);
      pr = __builtin_fmaf(pr, wsr, 2.83297682f);
      p = (lg <= LG2_W5) ? pr : p;
    }
    sum = __builtin_fmaf(p * u, NRM_C256, sum);  // 1/256 folded (exact 2^-8)
  }
  sum = dpp_reduce63(sum);            // VALU-pipe reduce; total in lane 63
  if (lane == 63) ws[b * NSTEPS + s] = sum;
}

// ---- B-fragment machinery, k-PERMUTED (unchanged from R20/R23/R26):
// B dword d of K-chunk T (lane q,n) holds W2 rows (16T+4q+d, 64+16T+4q+d)
// at column 16*(4*half+C) + n, f16x2 packed.
#define BDECL(T, C) u32x4 b_##T##_##C;
#define BINIT(T, C) { \
  const int col_ = 16 * (4 * half + (C)) + n; \
  const int r0_ = 16 * (T) + 4 * q; \
  b_##T##_##C = (u32x4){ \
    pack_f16x2(W2src[(r0_ + 0) * 128 + col_], W2src[(r0_ + 64) * 128 + col_]), \
    pack_f16x2(W2src[(r0_ + 1) * 128 + col_], W2src[(r0_ + 65) * 128 + col_]), \
    pack_f16x2(W2src[(r0_ + 2) * 128 + col_], W2src[(r0_ + 66) * 128 + col_]), \
    pack_f16x2(W2src[(r0_ + 3) * 128 + col_], W2src[(r0_ + 67) * 128 + col_])}; \
  asm volatile("" : "+a"(b_##T##_##C)); /* pin in AGPR quad */ \
}
#define MFMA1(ACC, AF, BF) \
  asm("v_mfma_f32_16x16x32_f16 %0, %1, %2, %0" : "+v"(ACC) : "v"(AF), "a"(BF));

// one-eval layer-1 for a batch: anchor A_, mid-time TV; writes regions
// 0=val, 1=d/dr*64, 2=d/dt_j*1024 (region 3 pre-zeroed).
#define STAGE3M(TV, SLOT, A_) { \
  float pre_ = __builtin_fmaf((TV), w11, __builtin_fmaf((A_), w10, c1)); \
  float e_ = eigen_erf_fast(pre_ * INV_SQRT2); \
  float cg_ = (e_ + 1.0f) * 0.5f; \
  float v_ = pre_ * cg_; \
  float ph_ = PHI_C * __expf(-0.5f * pre_ * pre_); \
  float gp_ = __builtin_fmaf(pre_, ph_, cg_); \
  ((uint16_t*)&h1x[SLOT][mlp][0][0])[2 * lane + half] = f32_to_f16bits(v_); \
  ((uint16_t*)&h1x[SLOT][mlp][1][0])[2 * lane + half] = f32_to_f16bits(gp_ * w10S); \
  ((uint16_t*)&h1x[SLOT][mlp][2][0])[2 * lane + half] = f32_to_f16bits(gp_ * w11T); \
}

// ---------------- Phase 2: scan, 64 blocks x 256 ---------------------------
__global__
__attribute__((amdgpu_flat_work_group_size(256, 256)))
__attribute__((amdgpu_waves_per_eu(1, 1)))
void vasicek_phase2_scan(
    const float* __restrict__ X, const float* __restrict__ r_ult,
    const float* __restrict__ mats,
    const float* __restrict__ Wp, const float* __restrict__ bp,
    const float* __restrict__ ln_g, const float* __restrict__ ln_b,
    const float* __restrict__ muW1, const float* __restrict__ mub1,
    const float* __restrict__ muW2, const float* __restrict__ mub2,
    const float* __restrict__ muW3, const float* __restrict__ mub3,
    const float* __restrict__ siW1, const float* __restrict__ sib1,
    const float* __restrict__ siW2, const float* __restrict__ sib2,
    const float* __restrict__ siW3, const float* __restrict__ sib3,
    const float* __restrict__ ws, float* __restrict__ out) {
  // [slot][mlp][region: 0=val,1=dr,2=dt,3=zero][68 dw] (stride 272B==16 mod 128)
  __shared__ __align__(16) uint32_t h1x[2][2][4][68];
  __shared__ __align__(16) float meanw[MWPAD];
  __shared__ float part[256];
  __shared__ float part2[256];
  __shared__ float ctx_lds[192];
  __shared__ __align__(16) float msum[2][4][4];   // [slot][wave][PV,PR,PT,pad]

  const int t = threadIdx.x;
  const int b = blockIdx.x;
  const int lane = t & 63;
  const int wv = t >> 6;

  for (int i = t; i < MWPAD; i += 256)
    meanw[i] = i < NSTEPS ? ws[b * NSTEPS + i] : 0.f;

  // ---- context aggregator (all 256 threads, one T-row each) ----
  float h[64];
  {
    float x0 = X[(b * NT + t) * 2 + 0];
    float x1 = X[(b * NT + t) * 2 + 1];
    float s = 0.f;
#pragma unroll
    for (int c = 0; c < 64; ++c) {
      float pre = __builtin_fmaf(x1, Wp[64 + c], x0 * Wp[c]) + bp[c];
      h[c] = eigen_tanh(pre);
      s += h[c];
    }
    float m = s * 0.015625f;
    float vs = 0.f;
#pragma unroll
    for (int c = 0; c < 64; ++c) { float d = h[c] - m; vs = __builtin_fmaf(d, d, vs); }
    float den = sqrtf(vs * 0.015625f + 1e-5f);
#pragma unroll
    for (int c = 0; c < 64; ++c)
      h[c] = ((h[c] - m) / den) * ln_g[c] + ln_b[c];
  }
  // fused T-reduction: sum and sumsq per channel on the VALU pipe (DPP)
#pragma unroll
  for (int c = 0; c < 64; ++c) {
    float v = h[c];
    float v2 = v * v;
    dpp_reduce63_2(v, v2);
    if (lane == 63) { part[wv * 64 + c] = v; part2[wv * 64 + c] = v2; }
  }
  if (t == 255) {
#pragma unroll
    for (int c = 0; c < 64; ++c) ctx_lds[128 + c] = h[c];
  }
  __syncthreads();
  if (t < 64) {
    float S1 = (part[t] + part[64 + t]) + (part[128 + t] + part[192 + t]);
    float S2 = (part2[t] + part2[64 + t]) + (part2[128 + t] + part2[192 + t]);
    float m = S1 * 0.00390625f;                    // /256
    ctx_lds[t] = m;
    float vs = fmaxf(__builtin_fmaf(-S1, m, S2), 0.f);  // = sum((h-m)^2)
    ctx_lds[64 + t] = sqrtf(vs / 255.0f);
  }
  __syncthreads();

  // ---- per-wave roles: mlp = wv>>1 (0=mu,1=si), half = wv&1 ----
  const int mlp = wv >> 1;
  const int half = wv & 1;
  const int jH = 64 * half + lane;            // layer-1 element ownership
  const float* W1 = mlp == 0 ? muW1 : siW1;
  const float* W2src = mlp == 0 ? muW2 : siW2;
  // c1 mat-vec: 4 independent accumulators, batched loads (ILP)
  float c10 = (mlp == 0 ? mub1 : sib1)[jH];
  float c11 = 0.f, c12 = 0.f, c13 = 0.f;
#pragma unroll 8
  for (int c = 0; c < 192; c += 4) {
    c10 = __builtin_fmaf(ctx_lds[c],     W1[(2 + c) * 128 + jH], c10);
    c11 = __builtin_fmaf(ctx_lds[c + 1], W1[(3 + c) * 128 + jH], c11);
    c12 = __builtin_fmaf(ctx_lds[c + 2], W1[(4 + c) * 128 + jH], c12);
    c13 = __builtin_fmaf(ctx_lds[c + 3], W1[(5 + c) * 128 + jH], c13);
  }
  const float c1 = (c10 + c11) + (c12 + c13);
  const float w10 = W1[jH], w11 = W1[128 + jH];
  const float w10S = w10 * TSC;
  const float w11T = w11 * (TSTEP * TSC_T);
  const float b3mu = mub3[0], b3si = sib3[0];

  const int q = lane >> 4, n = lane & 15;

  // per-lane epilogue constants: this lane's single column (chunk C = q)
  const float* b2p = mlp == 0 ? mub2 : sib2;
  const float* w3p = mlp == 0 ? muW3 : siW3;
  const int colE = 64 * half + 16 * q + n;
  const float b2E = b2p[colE], w3E = w3p[colE];

  // this wave's 4 col-tiles of its W2 -> 16 AGPR quads (one-time; pinned)
  BDECL(0,0) BDECL(0,1) BDECL(0,2) BDECL(0,3)
  BDECL(1,0) BDECL(1,1) BDECL(1,2) BDECL(1,3)
  BDECL(2,0) BDECL(2,1) BDECL(2,2) BDECL(2,3)
  BDECL(3,0) BDECL(3,1) BDECL(3,2) BDECL(3,3)
  BINIT(0,0) BINIT(0,1) BINIT(0,2) BINIT(0,3)
  BINIT(1,0) BINIT(1,1) BINIT(1,2) BINIT(1,3)
  BINIT(2,0) BINIT(2,1) BINIT(2,2) BINIT(2,3)
  BINIT(3,0) BINIT(3,1) BINIT(3,2) BINIT(3,3)

  // zero region 3 (A-rows 3,7,11,15) for both slots of this wave's MLP
  h1x[0][mlp][3][lane] = 0u; h1x[1][mlp][3][lane] = 0u;
  if (lane < 4) { h1x[0][mlp][3][64 + lane] = 0u; h1x[1][mlp][3][64 + lane] = 0u; }

  // A-frag base pointers: region (n&3) of this wave's MLP, quad offset q.
  const u32x4* hq0 = ((const u32x4*)&h1x[0][mlp][0][0]) + 17 * (n & 3) + q;
  const u32x4* hq1 = ((const u32x4*)&h1x[1][mlp][0][0]) + 17 * (n & 3) + q;

  // ---- scan state (uniform) + per-lane area ----
  const float r0 = r_ult[b];
  float r_s = r0;
  float aNow = r0, aUpd = r0, aMid = r0;   // anchors: batch k, k+1, k+2
  float area_p = 0.f;
  const int sj = lane;                     // lane = step-PAIR index (2sj,2sj+1)
  const float jjA = 2.0f * (float)sj - 63.5f;
  const float jjB = jjA + 1.0f;

  // ---- prologue: layer-1 one-eval for batch 0 -> slot 0, anchor r0 ----
  STAGE3M(TSTEP * 63.5f, 0, r0)
  __syncthreads();

  // ---- main loop: body k: scan batch k, MFMA batch k+1, STAGE3 batch k+2
#pragma unroll 1
  for (int k = -1; k < NBODY; ++k) {
    const int sl = k & 1;        // msum slot (batch k); h1 write slot (batch k+2)
    const int so = sl ^ 1;       // h1 read slot (batch k+1); msum write slot

    // --- LDS reads issued early ---
    f32x4 m0 = *(const f32x4*)&msum[sl][0][0];
    f32x4 m1 = *(const f32x4*)&msum[sl][1][0];
    f32x4 m2 = *(const f32x4*)&msum[sl][2][0];
    f32x4 m3 = *(const f32x4*)&msum[sl][3][0];
    const int u0 = k < 0 ? 0 : 128 * k;
    const float2 mw2 = *(const float2*)&meanw[u0 + 2 * sj];
    const u32x4* hq = so ? hq1 : hq0;
    u32x4 af0 = hq[0], af1 = hq[4], af2 = hq[8], af3 = hq[12];

    // --- MFMA batch k+1 (matrix pipe) ---
    f32x4 ac0 = {0,0,0,0}, ac1 = {0,0,0,0}, ac2 = {0,0,0,0}, ac3 = {0,0,0,0};
    MFMA1(ac0, af0, b_0_0) MFMA1(ac1, af0, b_0_1) MFMA1(ac2, af0, b_0_2) MFMA1(ac3, af0, b_0_3)
    MFMA1(ac0, af1, b_1_0) MFMA1(ac1, af1, b_1_1) MFMA1(ac2, af1, b_1_2) MFMA1(ac3, af1, b_1_3)
    MFMA1(ac0, af2, b_2_0) MFMA1(ac1, af2, b_2_1) MFMA1(ac2, af2, b_2_2) MFMA1(ac3, af2, b_2_3)
    MFMA1(ac0, af3, b_3_0) MFMA1(ac1, af3, b_3_1) MFMA1(ac2, af3, b_3_2) MFMA1(ac3, af3, b_3_3)

    // --- STAGE3 batch k+2 (anchor aMid from previous rotation) ---
    STAGE3M(TSTEP * ((float)(128 * (k + 2)) + 63.5f), sl, aMid)

    // --- affine scan for batch k (lane sj = steps 128k+2sj, 128k+2sj+1) ---
    {
      float MV = (m0[0] + m1[0]) + b3mu;
      float MR = (m0[1] + m1[1]) * TSC_INV;
      float MT = (m0[2] + m1[2]) * TSCT_INV;
      float ZV = (m2[0] + m3[0]) + b3si;
      float ZR = (m2[1] + m3[1]) * TSC_INV;
      float ZT = (m2[2] + m3[2]) * TSCT_INV;
      // softplus at z_mid + 2nd-order Taylor in the time offset
      float e_ = __expf(-fabsf(ZV));
      float sp = fmaxf(ZV, 0.f) + __logf(1.0f + e_) + 1e-5f;
      float inv = fast_rcp(1.0f + e_);
      float sgm = ZV > 0.f ? inv : 1.0f - inv;
      float hcv = 0.5f * sgm * (1.0f - sgm);
      // step A coefficients
      float dztA = jjA * ZT;
      float sigA = __builtin_fmaf(2.0f * hcv, dztA, sgm);
      float spA  = __builtin_fmaf(__builtin_fmaf(hcv, dztA, sgm), dztA, sp);
      float sZRA = sigA * ZR;
      float betaA = __builtin_fmaf(sZRA, mw2.x, __builtin_fmaf(MR, DTF, 1.0f));
      float amA = __builtin_fmaf(jjA, MT, __builtin_fmaf(-aNow, MR, MV));
      float asA = __builtin_fmaf(-aNow, sZRA, spA);
      float alphaA = __builtin_fmaf(amA, DTF, asA * mw2.x);
      // step B coefficients
      float dztB = jjB * ZT;
      float sigB = __builtin_fmaf(2.0f * hcv, dztB, sgm);
      float spB  = __builtin_fmaf(__builtin_fmaf(hcv, dztB, sgm), dztB, sp);
      float sZRB = sigB * ZR;
      float betaB = __builtin_fmaf(sZRB, mw2.y, __builtin_fmaf(MR, DTF, 1.0f));
      float amB = __builtin_fmaf(jjB, MT, __builtin_fmaf(-aNow, MR, MV));
      float asB = __builtin_fmaf(-aNow, sZRB, spB);
      float alphaB = __builtin_fmaf(amB, DTF, asB * mw2.y);
      // pair compose: step A then step B
      float B = betaB * betaA;
      float A = __builtin_fmaf(betaB, alphaA, alphaB);
      // inclusive affine prefix scan over 64 lanes (= 128 steps):
      {
        float Bs = dpp_mov<0x111, 0xf>(B, 1.0f), As = dpp_mov<0x111, 0xf>(A, 0.0f);
        A = __builtin_fmaf(B, As, A); B = B * Bs;
        Bs = dpp_mov<0x112, 0xf>(B, 1.0f); As = dpp_mov<0x112, 0xf>(A, 0.0f);
        A = __builtin_fmaf(B, As, A); B = B * Bs;
        Bs = dpp_mov<0x114, 0xf>(B, 1.0f); As = dpp_mov<0x114, 0xf>(A, 0.0f);
        A = __builtin_fmaf(B, As, A); B = B * Bs;
        Bs = dpp_mov<0x118, 0xf>(B, 1.0f); As = dpp_mov<0x118, 0xf>(A, 0.0f);
        A = __builtin_fmaf(B, As, A); B = B * Bs;
        Bs = dpp_mov<0x142, 0xa>(B, 1.0f); As = dpp_mov<0x142, 0xa>(A, 0.0f);
        A = __builtin_fmaf(B, As, A); B = B * Bs;
        Bs = dpp_mov<0x143, 0xc>(B, 1.0f); As = dpp_mov<0x143, 0xc>(A, 0.0f);
        A = __builtin_fmaf(B, As, A); B = B * Bs;
      }
      float rhoB = __builtin_fmaf(B, r_s, A);      // state after step 2sj+1
      if (k >= 0) {
        // state before this lane's pair: full-wave shfl_up by 1 (lane0 -> r_s)
        float prev = __shfl_up(rhoB, 1, 64);
        prev = sj == 0 ? r_s : prev;
        float rhoA = __builtin_fmaf(betaA, prev, alphaA);  // after step 2sj
        const int s0 = 128 * k + 2 * sj;
        float ca = s0 < NSTEPS ? rhoA * DTF : 0.f;
        float cb = (s0 + 1) < NSTEPS ? rhoB * DTF : 0.f;
        area_p += ca + cb;
        float rn = readlane_f(rhoB, 63);
        // drift-only prediction for batch k+3 (mid-step distance ~191.5)
        float aNew = __builtin_fmaf(MV, 191.5f * DTF, rn);
        r_s = rn;
        aNow = aUpd; aUpd = aMid; aMid = aNew;
      }
    }

    // --- MFMA dst -> VALU read hazard fence ---
    asm volatile("s_nop 7\n\ts_nop 7"
                 : "+v"(ac0), "+v"(ac1), "+v"(ac2), "+v"(ac3));

    // --- epilogue batch k+1: lane (q,n) handles its single column (C=q) ---
    {
      const f32x4 aq = q == 0 ? ac0 : q == 1 ? ac1 : q == 2 ? ac2 : ac3;
      float yv = aq[0] + b2E;
      float ytr = aq[1];                 // d/dr row (scaled TSC)
      float ytt = aq[2];                 // d/dt row (scaled TSC_T)
      float ev = eigen_erf_fast(yv * INV_SQRT2);
      float cv = (ev + 1.0f) * 0.5f;
      float pv = yv * cv * w3E;
      float phv = PHI_C * __expf(-0.5f * yv * yv);
      float g2p = __builtin_fmaf(yv, phv, cv) * w3E;
      float pr = g2p * ytr;
      float pt = g2p * ytt;
      pv = dpp_reduce63(pv);
      pr = dpp_reduce63(pr);
      pt = dpp_reduce63(pt);
      if (lane == 63) {
        *(f32x4*)&msum[so][wv][0] = (f32x4){pv, pr, pt, 0.f};
      }
    }
    __syncthreads();  // publish msum[so] (batch k+1) + h1x[sl] (batch k+2)
  }

  // area: lanes hold per-pair partials
  float area = area_p;
  area += __shfl_xor(area, 1, 64);
  area += __shfl_xor(area, 2, 64);
  area += __shfl_xor(area, 4, 64);
  area += __shfl_xor(area, 8, 64);
  area += __shfl_xor(area, 16, 64);
  area += __shfl_xor(area, 32, 64);

  if (t < NMAT) {
    float mx = mats[0];
#pragma unroll
    for (int i = 1; i < NMAT; ++i) mx = fmaxf(mx, mats[i]);
    const float mm = mats[t];
    const float frac = mm / (mx + 1e-12f);
    out[b * NMAT + t] = (area * frac) / (mm + 1e-12f);
  }
}

extern "C" void kernel_launch(void* const* d_in, const int* in_sizes, int n_in,
                              void* d_out, int out_size, void* d_ws, size_t ws_size,
                              hipStream_t stream) {
  (void)in_sizes; (void)n_in; (void)ws_size; (void)out_size;
  const float* X      = (const float*)d_in[0];
  const float* r_ult  = (const float*)d_in[1];
  const float* mats   = (const float*)d_in[2];
  const float* Wp     = (const float*)d_in[3];
  const float* bp     = (const float*)d_in[4];
  const float* ln_g   = (const float*)d_in[5];
  const float* ln_b   = (const float*)d_in[6];
  const float* muW1   = (const float*)d_in[7];
  const float* mub1   = (const float*)d_in[8];
  const float* muW2   = (const float*)d_in[9];
  const float* mub2   = (const float*)d_in[10];
  const float* muW3   = (const float*)d_in[11];
  const float* mub3   = (const float*)d_in[12];
  const float* siW1   = (const float*)d_in[13];
  const float* sib1   = (const float*)d_in[14];
  const float* siW2   = (const float*)d_in[15];
  const float* sib2   = (const float*)d_in[16];
  const float* siW3   = (const float*)d_in[17];
  const float* sib3   = (const float*)d_in[18];
  float* ws = (float*)d_ws;   // 64*2520*4 = 645,120 bytes

  hipLaunchKernelGGL(vasicek_phase1_meandw,
                     dim3(NB * NSTEPS / 4), dim3(256), 0, stream, ws);
  hipLaunchKernelGGL(vasicek_phase2_scan,
                     dim3(NB), dim3(256), 0, stream,
                     X, r_ult, mats, Wp, bp, ln_g, ln_b,
                     muW1, mub1, muW2, mub2, muW3, mub3,
                     siW1, sib1, siW2, sib2, siW3, sib3,
                     ws, (float*)d_out);
}